// Round 1
// baseline (1474.132 us; speedup 1.0000x reference)
//
#include <hip/hip_runtime.h>
#include <hip/hip_bf16.h>

#define LRELU(x) ((x) >= 0.f ? (x) : 0.01f * (x))

__device__ inline unsigned fenc(float x) {
    unsigned u = __float_as_uint(x);
    return (u & 0x80000000u) ? ~u : (u | 0x80000000u);
}
__device__ inline float fdec(unsigned e) {
    return __uint_as_float((e & 0x80000000u) ? (e ^ 0x80000000u) : ~e);
}

__device__ inline float wred(float v) {
#pragma unroll
    for (int o = 32; o > 0; o >>= 1) v += __shfl_xor(v, o, 64);
    return v;
}

// ---- relation dots: er1[r] = r_emb[r]·a_r1, er2[r] = r_emb[r]·a_r2 ----
__global__ __launch_bounds__(256) void k_rel(const float* __restrict__ remb,
                                             const float* __restrict__ ar1,
                                             const float* __restrict__ ar2,
                                             float* __restrict__ er1,
                                             float* __restrict__ er2, int NR) {
    int lane = threadIdx.x & 63;
    int r = blockIdx.x * 4 + (threadIdx.x >> 6);
    if (r >= NR) return;
    float v0 = remb[(size_t)r * 128 + lane];
    float v1 = remb[(size_t)r * 128 + 64 + lane];
    float p1 = v0 * ar1[lane] + v1 * ar1[64 + lane];
    float p2 = v0 * ar2[lane] + v1 * ar2[64 + lane];
    p1 = wred(p1);
    p2 = wred(p2);
    if (lane == 0) { er1[r] = p1; er2[r] = p2; }
}

// ---- fused projection: x_r_h = relu(x_e@w_h), x_r_t = relu(x_e@w_t) ----
// 256 threads: cols 0..127 -> w_h output, 128..255 -> w_t output. 16 rows/block,
// x_e row values are wave-uniform (scalar loads), W columns coalesced from L2.
#define TMP 16
__global__ __launch_bounds__(256) void k_proj(const float* __restrict__ xe,
                                              const float* __restrict__ wh,
                                              const float* __restrict__ wt,
                                              float* __restrict__ xrh,
                                              float* __restrict__ xrt, int NE) {
    int c = threadIdx.x;
    int row0 = blockIdx.x * TMP;
    if (row0 + TMP > NE) row0 = NE - TMP;
    const float* Wb = (c < 128) ? wh : wt;
    int cc = c & 127;
    float acc[TMP];
#pragma unroll
    for (int r = 0; r < TMP; r++) acc[r] = 0.f;
    const float* xr = xe + (size_t)row0 * 256;
    for (int k = 0; k < 256; k++) {
        float w = Wb[(size_t)k * 128 + cc];
#pragma unroll
        for (int r = 0; r < TMP; r++) acc[r] = fmaf(xr[(size_t)r * 256 + k], w, acc[r]);
    }
    float* Ob = (c < 128) ? xrh : xrt;
#pragma unroll
    for (int r = 0; r < TMP; r++)
        Ob[((size_t)row0 + r) * 128 + cc] = fmaxf(acc[r], 0.f);
}

// ---- per-entity scalar dots + ||x_r_t|| ----
__global__ __launch_bounds__(256) void k_dots(
    const float* __restrict__ xrh, const float* __restrict__ xrt,
    const float* __restrict__ ah1, const float* __restrict__ ah2,
    const float* __restrict__ ah3, const float* __restrict__ ah4,
    const float* __restrict__ at1, const float* __restrict__ at2,
    const float* __restrict__ at3, float* __restrict__ o_eh1,
    float* __restrict__ o_eh2, float* __restrict__ o_eh3,
    float* __restrict__ o_eh4, float* __restrict__ o_et1,
    float* __restrict__ o_et2, float* __restrict__ o_et3,
    float* __restrict__ o_nrm, int NE) {
    int lane = threadIdx.x & 63;
    int n = blockIdx.x * 4 + (threadIdx.x >> 6);
    if (n >= NE) return;
    float h0 = xrh[(size_t)n * 128 + lane], h1 = xrh[(size_t)n * 128 + 64 + lane];
    float t0 = xrt[(size_t)n * 128 + lane], t1 = xrt[(size_t)n * 128 + 64 + lane];
    float p;
    p = wred(h0 * ah1[lane] + h1 * ah1[64 + lane]); if (!lane) o_eh1[n] = p;
    p = wred(h0 * ah2[lane] + h1 * ah2[64 + lane]); if (!lane) o_eh2[n] = p;
    p = wred(h0 * ah3[lane] + h1 * ah3[64 + lane]); if (!lane) o_eh3[n] = p;
    p = wred(h0 * ah4[lane] + h1 * ah4[64 + lane]); if (!lane) o_eh4[n] = p;
    p = wred(t0 * at1[lane] + t1 * at1[64 + lane]); if (!lane) o_et1[n] = p;
    p = wred(t0 * at2[lane] + t1 * at2[64 + lane]); if (!lane) o_et2[n] = p;
    p = wred(t0 * at3[lane] + t1 * at3[64 + lane]); if (!lane) o_et3[n] = p;
    p = wred(t0 * t0 + t1 * t1);                    if (!lane) o_nrm[n] = sqrtf(p);
}

// ---- level 1 softmax passes over triple_num segments ----
__global__ __launch_bounds__(256) void k_edge1(
    const int* __restrict__ hidx, const int* __restrict__ tidx,
    const int* __restrict__ rel, const int* __restrict__ tnum,
    const float* __restrict__ eh1, const float* __restrict__ et1,
    const float* __restrict__ er1, float* __restrict__ zbuf,
    unsigned* __restrict__ m1, int E) {
    int i = blockIdx.x * 256 + threadIdx.x;
    if (i >= E) return;
    float e1 = 0.5f * (eh1[hidx[i]] + et1[tidx[i]]) + er1[rel[i]];
    float z = LRELU(e1);
    zbuf[i] = z;
    atomicMax(&m1[tnum[i]], fenc(z));
}

__global__ __launch_bounds__(256) void k_edge2(const int* __restrict__ tnum,
                                               float* __restrict__ zbuf,
                                               const unsigned* __restrict__ m1,
                                               float* __restrict__ s1, int E) {
    int i = blockIdx.x * 256 + threadIdx.x;
    if (i >= E) return;
    int tn = tnum[i];
    float ex = expf(zbuf[i] - fdec(m1[tn]));
    zbuf[i] = ex;
    atomicAdd(&s1[tn], ex);
}

// ---- alpha -> per-edge scale s, level-2 logit, segment max over class ----
__global__ __launch_bounds__(256) void k_edge3(
    const int* __restrict__ hidx, const int* __restrict__ tidx,
    const int* __restrict__ rel, const int* __restrict__ tnum,
    const int* __restrict__ cidx, const float* __restrict__ zbuf,
    const float* __restrict__ s1, const float* __restrict__ nrm,
    const float* __restrict__ eh2, const float* __restrict__ eh3,
    const float* __restrict__ et2, const float* __restrict__ et3,
    const float* __restrict__ er2, float* __restrict__ sbuf,
    float* __restrict__ e2buf, unsigned* __restrict__ m2, int E) {
    int i = blockIdx.x * 256 + threadIdx.x;
    if (i >= E) return;
    float alpha = zbuf[i] / (s1[tnum[i]] + 1e-16f);
    int t = tidx[i];
    float s = alpha / fmaxf(alpha * nrm[t], 1e-12f);
    sbuf[i] = s;
    int h = hidx[i];
    float z2 = s * et2[t] + eh2[h] + 0.5f * (er2[rel[i]] + 0.5f * (eh3[h] + s * et3[t]));
    z2 = LRELU(z2);
    e2buf[i] = z2;
    atomicMax(&m2[cidx[i]], fenc(z2));
}

__global__ __launch_bounds__(256) void k_edge4(const int* __restrict__ cidx,
                                               float* __restrict__ e2buf,
                                               const unsigned* __restrict__ m2,
                                               float* __restrict__ s2, int E) {
    int i = blockIdx.x * 256 + threadIdx.x;
    if (i >= E) return;
    int ci = cidx[i];
    float ex = expf(e2buf[i] - fdec(m2[ci]));
    e2buf[i] = ex;
    atomicAdd(&s2[ci], ex);
}

// ---- spmm: x_class[ci] += beta_i * s[t_idx[i]] * x_r_t[t_idx[t_idx[i]]] ----
__global__ __launch_bounds__(256) void k_spmm(
    const int* __restrict__ tidx, const int* __restrict__ cidx,
    const float* __restrict__ ex2, const float* __restrict__ s2,
    const float* __restrict__ sbuf, const float* __restrict__ xrt,
    float* __restrict__ xclass, int E) {
    int lane = threadIdx.x & 63;
    int wv = blockIdx.x * 4 + (threadIdx.x >> 6);
    int nw = gridDim.x * 4;
    for (int i0 = wv; i0 < E; i0 += nw) {
        int i = __builtin_amdgcn_readfirstlane(i0);
        int ci = cidx[i];
        float beta = ex2[i] / (s2[ci] + 1e-16f);
        int te = tidx[i];
        float w = beta * sbuf[te];
        int g = tidx[te];
        float v0 = xrt[(size_t)g * 128 + lane];
        float v1 = xrt[(size_t)g * 128 + 64 + lane];
        atomicAdd(&xclass[(size_t)ci * 128 + lane], w * v0);
        atomicAdd(&xclass[(size_t)ci * 128 + 64 + lane], w * v1);
    }
}

// ---- level 3: class -> head entity ----
__global__ __launch_bounds__(256) void k_class1(
    const float* __restrict__ xclass, const float* __restrict__ ac,
    const float* __restrict__ eh4, const int* __restrict__ hclass,
    float* __restrict__ zc, unsigned* __restrict__ m3, int NC) {
    int lane = threadIdx.x & 63;
    int c = blockIdx.x * 4 + (threadIdx.x >> 6);
    if (c >= NC) return;
    float v0 = xclass[(size_t)c * 128 + lane], v1 = xclass[(size_t)c * 128 + 64 + lane];
    float p = wred(v0 * ac[lane] + v1 * ac[64 + lane]);
    if (lane == 0) {
        int hc = hclass[c];
        float z = LRELU(p + eh4[hc]);
        zc[c] = z;
        atomicMax(&m3[hc], fenc(z));
    }
}

__global__ __launch_bounds__(256) void k_class2(const int* __restrict__ hclass,
                                                float* __restrict__ zc,
                                                const unsigned* __restrict__ m3,
                                                float* __restrict__ s3, int NC) {
    int c = blockIdx.x * 256 + threadIdx.x;
    if (c >= NC) return;
    int hc = hclass[c];
    float ex = expf(zc[c] - fdec(m3[hc]));
    zc[c] = ex;
    atomicAdd(&s3[hc], ex);
}

__global__ __launch_bounds__(256) void k_class3(
    const int* __restrict__ hclass, const float* __restrict__ zc,
    const float* __restrict__ s3, const float* __restrict__ xclass,
    float* __restrict__ xeh, int NC) {
    int lane = threadIdx.x & 63;
    int c = blockIdx.x * 4 + (threadIdx.x >> 6);
    if (c >= NC) return;
    int hc = hclass[c];
    float gama = zc[c] / (s3[hc] + 1e-16f);
    float v0 = xclass[(size_t)c * 128 + lane], v1 = xclass[(size_t)c * 128 + 64 + lane];
    atomicAdd(&xeh[(size_t)hc * 128 + lane], gama * v0);
    atomicAdd(&xeh[(size_t)hc * 128 + 64 + lane], gama * v1);
}

// ---- highway gate GEMM + combine ----
#define TMF 16
__global__ __launch_bounds__(256) void k_final(const float* __restrict__ xrh,
                                               const float* __restrict__ xeh,
                                               const float* __restrict__ hww,
                                               const float* __restrict__ hwb,
                                               float* __restrict__ out, int NE) {
    __shared__ float lw[128 * 128];
    for (int i = threadIdx.x; i < 128 * 128; i += 256) lw[i] = hww[i];
    __syncthreads();
    int c = threadIdx.x & 127;
    int grp = threadIdx.x >> 7;  // 0 or 1
    int row0 = blockIdx.x * TMF;
    if (row0 + TMF > NE) row0 = NE - TMF;
    float acc[TMF / 2];
#pragma unroll
    for (int r = 0; r < TMF / 2; r++) acc[r] = 0.f;
    const float* xr = xrh + ((size_t)row0 + grp * (TMF / 2)) * 128;
    for (int k = 0; k < 128; k++) {
        float w = lw[k * 128 + c];
#pragma unroll
        for (int r = 0; r < TMF / 2; r++) acc[r] = fmaf(xr[(size_t)r * 128 + k], w, acc[r]);
    }
    float b = hwb[c];
#pragma unroll
    for (int r = 0; r < TMF / 2; r++) {
        size_t row = (size_t)row0 + grp * (TMF / 2) + r;
        float g = 1.f / (1.f + expf(-(acc[r] + b)));
        size_t o = row * 128 + c;
        out[o] = g * xeh[o] + (1.f - g) * xrh[o];
    }
}

extern "C" void kernel_launch(void* const* d_in, const int* in_sizes, int n_in,
                              void* d_out, int out_size, void* d_ws, size_t ws_size,
                              hipStream_t stream) {
    (void)n_in; (void)out_size; (void)ws_size;
    const float* xe   = (const float*)d_in[0];
    const int*   eidx = (const int*)d_in[1];
    const int*   rel  = (const int*)d_in[2];
    const int*   tnum = (const int*)d_in[3];
    const float* remb = (const float*)d_in[4];
    const int*   cidx = (const int*)d_in[5];
    const int*   hcls = (const int*)d_in[6];
    const float* ah1  = (const float*)d_in[7];
    const float* ah2  = (const float*)d_in[8];
    const float* ah3  = (const float*)d_in[9];
    const float* ah4  = (const float*)d_in[10];
    const float* at1  = (const float*)d_in[11];
    const float* at2  = (const float*)d_in[12];
    const float* at3  = (const float*)d_in[13];
    const float* ar1  = (const float*)d_in[14];
    const float* ar2  = (const float*)d_in[15];
    const float* ac   = (const float*)d_in[16];
    const float* wh   = (const float*)d_in[17];
    const float* wt   = (const float*)d_in[18];
    const float* hww  = (const float*)d_in[19];
    const float* hwb  = (const float*)d_in[20];
    float* out = (float*)d_out;

    const int NE = in_sizes[0] / 256;
    const int E  = in_sizes[2];
    const int NR = in_sizes[4] / 128;
    const int NC = in_sizes[6];
    const int* hidx = eidx;
    const int* tidx = eidx + E;

    char* base = (char*)d_ws;
    size_t off = 0;
    auto alloc = [&](size_t bytes) -> char* {
        char* r = base + off;
        off = (off + bytes + 255) & ~(size_t)255;
        return r;
    };
    float* xrh  = (float*)alloc((size_t)NE * 128 * 4);
    float* xrt  = (float*)alloc((size_t)NE * 128 * 4);
    float* eh1  = (float*)alloc((size_t)NE * 4);
    float* eh2  = (float*)alloc((size_t)NE * 4);
    float* eh3  = (float*)alloc((size_t)NE * 4);
    float* eh4  = (float*)alloc((size_t)NE * 4);
    float* et1b = (float*)alloc((size_t)NE * 4);
    float* et2b = (float*)alloc((size_t)NE * 4);
    float* et3b = (float*)alloc((size_t)NE * 4);
    float* nrmb = (float*)alloc((size_t)NE * 4);
    float* er1b = (float*)alloc((size_t)NR * 4);
    float* er2b = (float*)alloc((size_t)NR * 4);
    float* zbuf  = (float*)alloc((size_t)E * 4);
    float* e2buf = (float*)alloc((size_t)E * 4);
    float* sbuf  = (float*)alloc((size_t)E * 4);
    float* zc    = (float*)alloc((size_t)NC * 4);
    size_t zoff = off;  // everything below is zero-initialized
    unsigned* m1 = (unsigned*)alloc((size_t)NE * 4);
    float* s1    = (float*)alloc((size_t)NE * 4);
    unsigned* m2 = (unsigned*)alloc((size_t)NC * 4);
    float* s2    = (float*)alloc((size_t)NC * 4);
    unsigned* m3 = (unsigned*)alloc((size_t)NE * 4);
    float* s3    = (float*)alloc((size_t)NE * 4);
    float* xclass = (float*)alloc((size_t)NC * 128 * 4);
    float* xeh    = (float*)alloc((size_t)NE * 128 * 4);
    size_t zbytes = off - zoff;

    hipMemsetAsync(base + zoff, 0, zbytes, stream);

    k_rel<<<(NR + 3) / 4, 256, 0, stream>>>(remb, ar1, ar2, er1b, er2b, NR);
    k_proj<<<(NE + TMP - 1) / TMP, 256, 0, stream>>>(xe, wh, wt, xrh, xrt, NE);
    k_dots<<<(NE + 3) / 4, 256, 0, stream>>>(xrh, xrt, ah1, ah2, ah3, ah4, at1, at2, at3,
                                             eh1, eh2, eh3, eh4, et1b, et2b, et3b, nrmb, NE);
    k_edge1<<<(E + 255) / 256, 256, 0, stream>>>(hidx, tidx, rel, tnum, eh1, et1b, er1b, zbuf, m1, E);
    k_edge2<<<(E + 255) / 256, 256, 0, stream>>>(tnum, zbuf, m1, s1, E);
    k_edge3<<<(E + 255) / 256, 256, 0, stream>>>(hidx, tidx, rel, tnum, cidx, zbuf, s1, nrmb,
                                                 eh2, eh3, et2b, et3b, er2b, sbuf, e2buf, m2, E);
    k_edge4<<<(E + 255) / 256, 256, 0, stream>>>(cidx, e2buf, m2, s2, E);
    k_spmm<<<2048, 256, 0, stream>>>(tidx, cidx, e2buf, s2, sbuf, xrt, xclass, E);
    k_class1<<<(NC + 3) / 4, 256, 0, stream>>>(xclass, ac, eh4, hcls, zc, m3, NC);
    k_class2<<<(NC + 255) / 256, 256, 0, stream>>>(hcls, zc, m3, s3, NC);
    k_class3<<<(NC + 3) / 4, 256, 0, stream>>>(hcls, zc, s3, xclass, xeh, NC);
    k_final<<<(NE + TMF - 1) / TMF, 256, 0, stream>>>(xrh, xeh, hww, hwb, out, NE);
}

// Round 2
// 988.086 us; speedup vs baseline: 1.4919x; 1.4919x over previous
//
#include <hip/hip_runtime.h>
#include <hip/hip_bf16.h>

#define LRELU(x) ((x) >= 0.f ? (x) : 0.01f * (x))

typedef __attribute__((ext_vector_type(8))) short short8v;
typedef __attribute__((ext_vector_type(4))) float f32x4;

__device__ inline unsigned fenc(float x) {
    unsigned u = __float_as_uint(x);
    return (u & 0x80000000u) ? ~u : (u | 0x80000000u);
}
__device__ inline float fdec(unsigned e) {
    return __uint_as_float((e & 0x80000000u) ? (e ^ 0x80000000u) : ~e);
}

__device__ inline float wred(float v) {
#pragma unroll
    for (int o = 32; o > 0; o >>= 1) v += __shfl_xor(v, o, 64);
    return v;
}

__device__ inline unsigned short f2bu(float x) {
    __hip_bfloat16 b = __float2bfloat16(x);
    return *reinterpret_cast<unsigned short*>(&b);
}
__device__ inline float bu2f(unsigned short u) {
    return __uint_as_float((unsigned)u << 16);
}

__device__ inline f32x4 mfma16(short8v a, short8v b, f32x4 c) {
    return __builtin_amdgcn_mfma_f32_16x16x32_bf16(a, b, c, 0, 0, 0);
}

// ---- convert W matrices to transposed hi/lo bf16: Wt[n][k] = W[k][n] ----
__global__ __launch_bounds__(256) void k_convW(
    const float* __restrict__ wh, const float* __restrict__ wt,
    const float* __restrict__ hww, unsigned short* __restrict__ wtb_hi,
    unsigned short* __restrict__ wtb_lo, unsigned short* __restrict__ hwt_hi,
    unsigned short* __restrict__ hwt_lo) {
    int id = blockIdx.x * 256 + threadIdx.x;
    if (id < 256 * 256) {
        int n = id >> 8, k = id & 255;
        float v = (n < 128) ? wh[(size_t)k * 128 + n] : wt[(size_t)k * 128 + (n - 128)];
        unsigned short h = f2bu(v);
        float r = v - bu2f(h);
        wtb_hi[(size_t)n * 256 + k] = h;
        wtb_lo[(size_t)n * 256 + k] = f2bu(r);
    } else {
        int id2 = id - 256 * 256;
        if (id2 < 128 * 128) {
            int n = id2 >> 7, k = id2 & 127;
            float v = hww[(size_t)k * 128 + n];
            unsigned short h = f2bu(v);
            float r = v - bu2f(h);
            hwt_hi[(size_t)n * 128 + k] = h;
            hwt_lo[(size_t)n * 128 + k] = f2bu(r);
        }
    }
}

// ---- split-bf16 MFMA GEMM: C[M x 128] = A[M x KD] @ Wt^T, per-n0 block ----
// EPI 0: relu, store to o0 (n0==0) or o1 (n0==128)   [projection, KD=256]
// EPI 1: gate = sigmoid(C + bias); out = gate*xeh + (1-gate)*A  [highway, KD=128]
template <int KD, int EPI>
__global__ __launch_bounds__(256) void k_gemm(
    const float* __restrict__ A, const unsigned short* __restrict__ Bh,
    const unsigned short* __restrict__ Bl, float* __restrict__ o0,
    float* __restrict__ o1, const float* __restrict__ bias,
    const float* __restrict__ xeh, int M, int nBlk2) {
    int bx = blockIdx.x;
    int mblk = nBlk2 ? (bx >> 1) : bx;
    int n0 = nBlk2 ? ((bx & 1) << 7) : 0;
    int row0 = mblk * 128;
    if (row0 + 128 > M) row0 = M - 128;
    int tid = threadIdx.x;
    int w = tid >> 6, l = tid & 63;
    int lr = l & 15;
    int lk = (l >> 4) * 8;

    f32x4 acc[2][8];
#pragma unroll
    for (int i = 0; i < 2; i++)
#pragma unroll
        for (int j = 0; j < 8; j++) acc[i][j] = (f32x4){0.f, 0.f, 0.f, 0.f};

    const float* ap0 = A + (size_t)(row0 + w * 32 + lr) * KD + lk;
    const float* ap1 = ap0 + (size_t)16 * KD;
    const unsigned short* bp_h = Bh + (size_t)(n0 + lr) * KD + lk;
    const unsigned short* bp_l = Bl + (size_t)(n0 + lr) * KD + lk;

    for (int k0 = 0; k0 < KD; k0 += 32) {
        short8v ah[2], al[2];
#pragma unroll
        for (int rf = 0; rf < 2; rf++) {
            const float* ap = (rf ? ap1 : ap0) + k0;
            float4 xa = *(const float4*)ap;
            float4 xb = *(const float4*)(ap + 4);
            float xs[8] = {xa.x, xa.y, xa.z, xa.w, xb.x, xb.y, xb.z, xb.w};
#pragma unroll
            for (int j = 0; j < 8; j++) {
                unsigned short hu = f2bu(xs[j]);
                ah[rf][j] = (short)hu;
                al[rf][j] = (short)f2bu(xs[j] - bu2f(hu));
            }
        }
#pragma unroll
        for (int cf = 0; cf < 8; cf++) {
            const unsigned short* bph = bp_h + (size_t)(cf * 16) * KD + k0;
            const unsigned short* bpl = bp_l + (size_t)(cf * 16) * KD + k0;
            short8v bh = *(const short8v*)bph;
            short8v bl = *(const short8v*)bpl;
#pragma unroll
            for (int rf = 0; rf < 2; rf++) {
                acc[rf][cf] = mfma16(ah[rf], bh, acc[rf][cf]);
                acc[rf][cf] = mfma16(al[rf], bh, acc[rf][cf]);
                acc[rf][cf] = mfma16(ah[rf], bl, acc[rf][cf]);
            }
        }
    }

    if (EPI == 0) {
        float* O = n0 ? o1 : o0;
#pragma unroll
        for (int rf = 0; rf < 2; rf++)
#pragma unroll
            for (int cf = 0; cf < 8; cf++)
#pragma unroll
                for (int r = 0; r < 4; r++) {
                    int row = row0 + w * 32 + rf * 16 + (l >> 4) * 4 + r;
                    int col = cf * 16 + lr;
                    O[(size_t)row * 128 + col] = fmaxf(acc[rf][cf][r], 0.f);
                }
    } else {
#pragma unroll
        for (int rf = 0; rf < 2; rf++)
#pragma unroll
            for (int cf = 0; cf < 8; cf++)
#pragma unroll
                for (int r = 0; r < 4; r++) {
                    int row = row0 + w * 32 + rf * 16 + (l >> 4) * 4 + r;
                    int col = cf * 16 + lr;
                    float a = acc[rf][cf][r] + bias[col];
                    float g = 1.f / (1.f + expf(-a));
                    size_t o = (size_t)row * 128 + col;
                    o0[o] = g * xeh[o] + (1.f - g) * A[o];
                }
    }
}

// ---- relation dots ----
__global__ __launch_bounds__(256) void k_rel(const float* __restrict__ remb,
                                             const float* __restrict__ ar1,
                                             const float* __restrict__ ar2,
                                             float* __restrict__ er1,
                                             float* __restrict__ er2, int NR) {
    int lane = threadIdx.x & 63;
    int r = blockIdx.x * 4 + (threadIdx.x >> 6);
    if (r >= NR) return;
    float v0 = remb[(size_t)r * 128 + lane];
    float v1 = remb[(size_t)r * 128 + 64 + lane];
    float p1 = v0 * ar1[lane] + v1 * ar1[64 + lane];
    float p2 = v0 * ar2[lane] + v1 * ar2[64 + lane];
    p1 = wred(p1);
    p2 = wred(p2);
    if (lane == 0) { er1[r] = p1; er2[r] = p2; }
}

// ---- per-entity scalar dots + ||x_r_t|| ----
__global__ __launch_bounds__(256) void k_dots(
    const float* __restrict__ xrh, const float* __restrict__ xrt,
    const float* __restrict__ ah1, const float* __restrict__ ah2,
    const float* __restrict__ ah3, const float* __restrict__ ah4,
    const float* __restrict__ at1, const float* __restrict__ at2,
    const float* __restrict__ at3, float* __restrict__ o_eh1,
    float* __restrict__ o_eh2, float* __restrict__ o_eh3,
    float* __restrict__ o_eh4, float* __restrict__ o_et1,
    float* __restrict__ o_et2, float* __restrict__ o_et3,
    float* __restrict__ o_nrm, int NE) {
    int lane = threadIdx.x & 63;
    int n = blockIdx.x * 4 + (threadIdx.x >> 6);
    if (n >= NE) return;
    float h0 = xrh[(size_t)n * 128 + lane], h1 = xrh[(size_t)n * 128 + 64 + lane];
    float t0 = xrt[(size_t)n * 128 + lane], t1 = xrt[(size_t)n * 128 + 64 + lane];
    float p;
    p = wred(h0 * ah1[lane] + h1 * ah1[64 + lane]); if (!lane) o_eh1[n] = p;
    p = wred(h0 * ah2[lane] + h1 * ah2[64 + lane]); if (!lane) o_eh2[n] = p;
    p = wred(h0 * ah3[lane] + h1 * ah3[64 + lane]); if (!lane) o_eh3[n] = p;
    p = wred(h0 * ah4[lane] + h1 * ah4[64 + lane]); if (!lane) o_eh4[n] = p;
    p = wred(t0 * at1[lane] + t1 * at1[64 + lane]); if (!lane) o_et1[n] = p;
    p = wred(t0 * at2[lane] + t1 * at2[64 + lane]); if (!lane) o_et2[n] = p;
    p = wred(t0 * at3[lane] + t1 * at3[64 + lane]); if (!lane) o_et3[n] = p;
    p = wred(t0 * t0 + t1 * t1);                    if (!lane) o_nrm[n] = sqrtf(p);
}

// ---- level 1 softmax over triple_num segments ----
__global__ __launch_bounds__(256) void k_edge1(
    const int* __restrict__ hidx, const int* __restrict__ tidx,
    const int* __restrict__ rel, const int* __restrict__ tnum,
    const float* __restrict__ eh1, const float* __restrict__ et1,
    const float* __restrict__ er1, float* __restrict__ zbuf,
    unsigned* __restrict__ m1, int E) {
    int i = blockIdx.x * 256 + threadIdx.x;
    if (i >= E) return;
    float e1 = 0.5f * (eh1[hidx[i]] + et1[tidx[i]]) + er1[rel[i]];
    float z = LRELU(e1);
    zbuf[i] = z;
    atomicMax(&m1[tnum[i]], fenc(z));
}

__global__ __launch_bounds__(256) void k_edge2(const int* __restrict__ tnum,
                                               float* __restrict__ zbuf,
                                               const unsigned* __restrict__ m1,
                                               float* __restrict__ s1, int E) {
    int i = blockIdx.x * 256 + threadIdx.x;
    if (i >= E) return;
    int tn = tnum[i];
    float ex = expf(zbuf[i] - fdec(m1[tn]));
    zbuf[i] = ex;
    atomicAdd(&s1[tn], ex);
}

// ---- alpha -> per-edge scale s, level-2 logit, class segment max ----
__global__ __launch_bounds__(256) void k_edge3(
    const int* __restrict__ hidx, const int* __restrict__ tidx,
    const int* __restrict__ rel, const int* __restrict__ tnum,
    const int* __restrict__ cidx, const float* __restrict__ zbuf,
    const float* __restrict__ s1, const float* __restrict__ nrm,
    const float* __restrict__ eh2, const float* __restrict__ eh3,
    const float* __restrict__ et2, const float* __restrict__ et3,
    const float* __restrict__ er2, float* __restrict__ sbuf,
    float* __restrict__ e2buf, unsigned* __restrict__ m2, int E) {
    int i = blockIdx.x * 256 + threadIdx.x;
    if (i >= E) return;
    float alpha = zbuf[i] / (s1[tnum[i]] + 1e-16f);
    int t = tidx[i];
    float s = alpha / fmaxf(alpha * nrm[t], 1e-12f);
    sbuf[i] = s;
    int h = hidx[i];
    float z2 = s * et2[t] + eh2[h] + 0.5f * (er2[rel[i]] + 0.5f * (eh3[h] + s * et3[t]));
    z2 = LRELU(z2);
    e2buf[i] = z2;
    atomicMax(&m2[cidx[i]], fenc(z2));
}

__global__ __launch_bounds__(256) void k_edge4(const int* __restrict__ cidx,
                                               float* __restrict__ e2buf,
                                               const unsigned* __restrict__ m2,
                                               float* __restrict__ s2, int E) {
    int i = blockIdx.x * 256 + threadIdx.x;
    if (i >= E) return;
    int ci = cidx[i];
    float ex = expf(e2buf[i] - fdec(m2[ci]));
    e2buf[i] = ex;
    atomicAdd(&s2[ci], ex);
}

// ---- spmm: x_class[ci] += beta_i * s[t_idx[i]] * x_r_t[t_idx[t_idx[i]]] ----
__global__ __launch_bounds__(256) void k_spmm(
    const int* __restrict__ tidx, const int* __restrict__ cidx,
    const float* __restrict__ ex2, const float* __restrict__ s2,
    const float* __restrict__ sbuf, const float* __restrict__ xrt,
    float* __restrict__ xclass, int E) {
    int lane = threadIdx.x & 63;
    int wv = blockIdx.x * 4 + (threadIdx.x >> 6);
    int nw = gridDim.x * 4;
    for (int i0 = wv; i0 < E; i0 += nw) {
        int i = __builtin_amdgcn_readfirstlane(i0);
        int ci = cidx[i];
        float beta = ex2[i] / (s2[ci] + 1e-16f);
        int te = tidx[i];
        float w = beta * sbuf[te];
        int g = tidx[te];
        float v0 = xrt[(size_t)g * 128 + lane];
        float v1 = xrt[(size_t)g * 128 + 64 + lane];
        atomicAdd(&xclass[(size_t)ci * 128 + lane], w * v0);
        atomicAdd(&xclass[(size_t)ci * 128 + 64 + lane], w * v1);
    }
}

// ---- level 3: class -> head entity ----
__global__ __launch_bounds__(256) void k_class1(
    const float* __restrict__ xclass, const float* __restrict__ ac,
    const float* __restrict__ eh4, const int* __restrict__ hclass,
    float* __restrict__ zc, unsigned* __restrict__ m3, int NC) {
    int lane = threadIdx.x & 63;
    int c = blockIdx.x * 4 + (threadIdx.x >> 6);
    if (c >= NC) return;
    float v0 = xclass[(size_t)c * 128 + lane], v1 = xclass[(size_t)c * 128 + 64 + lane];
    float p = wred(v0 * ac[lane] + v1 * ac[64 + lane]);
    if (lane == 0) {
        int hc = hclass[c];
        float z = LRELU(p + eh4[hc]);
        zc[c] = z;
        atomicMax(&m3[hc], fenc(z));
    }
}

__global__ __launch_bounds__(256) void k_class2(const int* __restrict__ hclass,
                                                float* __restrict__ zc,
                                                const unsigned* __restrict__ m3,
                                                float* __restrict__ s3, int NC) {
    int c = blockIdx.x * 256 + threadIdx.x;
    if (c >= NC) return;
    int hc = hclass[c];
    float ex = expf(zc[c] - fdec(m3[hc]));
    zc[c] = ex;
    atomicAdd(&s3[hc], ex);
}

__global__ __launch_bounds__(256) void k_class3(
    const int* __restrict__ hclass, const float* __restrict__ zc,
    const float* __restrict__ s3, const float* __restrict__ xclass,
    float* __restrict__ xeh, int NC) {
    int lane = threadIdx.x & 63;
    int c = blockIdx.x * 4 + (threadIdx.x >> 6);
    if (c >= NC) return;
    int hc = hclass[c];
    float gama = zc[c] / (s3[hc] + 1e-16f);
    float v0 = xclass[(size_t)c * 128 + lane], v1 = xclass[(size_t)c * 128 + 64 + lane];
    atomicAdd(&xeh[(size_t)hc * 128 + lane], gama * v0);
    atomicAdd(&xeh[(size_t)hc * 128 + 64 + lane], gama * v1);
}

extern "C" void kernel_launch(void* const* d_in, const int* in_sizes, int n_in,
                              void* d_out, int out_size, void* d_ws, size_t ws_size,
                              hipStream_t stream) {
    (void)n_in; (void)out_size; (void)ws_size;
    const float* xe   = (const float*)d_in[0];
    const int*   eidx = (const int*)d_in[1];
    const int*   rel  = (const int*)d_in[2];
    const int*   tnum = (const int*)d_in[3];
    const float* remb = (const float*)d_in[4];
    const int*   cidx = (const int*)d_in[5];
    const int*   hcls = (const int*)d_in[6];
    const float* ah1  = (const float*)d_in[7];
    const float* ah2  = (const float*)d_in[8];
    const float* ah3  = (const float*)d_in[9];
    const float* ah4  = (const float*)d_in[10];
    const float* at1  = (const float*)d_in[11];
    const float* at2  = (const float*)d_in[12];
    const float* at3  = (const float*)d_in[13];
    const float* ar1  = (const float*)d_in[14];
    const float* ar2  = (const float*)d_in[15];
    const float* ac   = (const float*)d_in[16];
    const float* wh   = (const float*)d_in[17];
    const float* wt   = (const float*)d_in[18];
    const float* hww  = (const float*)d_in[19];
    const float* hwb  = (const float*)d_in[20];
    float* out = (float*)d_out;

    const int NE = in_sizes[0] / 256;
    const int E  = in_sizes[2];
    const int NR = in_sizes[4] / 128;
    const int NC = in_sizes[6];
    const int* hidx = eidx;
    const int* tidx = eidx + E;

    char* base = (char*)d_ws;
    size_t off = 0;
    auto alloc = [&](size_t bytes) -> char* {
        char* r = base + off;
        off = (off + bytes + 255) & ~(size_t)255;
        return r;
    };
    float* xrh  = (float*)alloc((size_t)NE * 128 * 4);
    float* xrt  = (float*)alloc((size_t)NE * 128 * 4);
    float* eh1  = (float*)alloc((size_t)NE * 4);
    float* eh2  = (float*)alloc((size_t)NE * 4);
    float* eh3  = (float*)alloc((size_t)NE * 4);
    float* eh4  = (float*)alloc((size_t)NE * 4);
    float* et1b = (float*)alloc((size_t)NE * 4);
    float* et2b = (float*)alloc((size_t)NE * 4);
    float* et3b = (float*)alloc((size_t)NE * 4);
    float* nrmb = (float*)alloc((size_t)NE * 4);
    float* er1b = (float*)alloc((size_t)NR * 4);
    float* er2b = (float*)alloc((size_t)NR * 4);
    float* zbuf  = (float*)alloc((size_t)E * 4);
    float* e2buf = (float*)alloc((size_t)E * 4);
    float* sbuf  = (float*)alloc((size_t)E * 4);
    float* zc    = (float*)alloc((size_t)NC * 4);
    unsigned short* wtb_hi = (unsigned short*)alloc((size_t)256 * 256 * 2);
    unsigned short* wtb_lo = (unsigned short*)alloc((size_t)256 * 256 * 2);
    unsigned short* hwt_hi = (unsigned short*)alloc((size_t)128 * 128 * 2);
    unsigned short* hwt_lo = (unsigned short*)alloc((size_t)128 * 128 * 2);
    size_t zoff = off;  // everything below is zero-initialized
    unsigned* m1 = (unsigned*)alloc((size_t)NE * 4);
    float* s1    = (float*)alloc((size_t)NE * 4);
    unsigned* m2 = (unsigned*)alloc((size_t)NC * 4);
    float* s2    = (float*)alloc((size_t)NC * 4);
    unsigned* m3 = (unsigned*)alloc((size_t)NE * 4);
    float* s3    = (float*)alloc((size_t)NE * 4);
    float* xclass = (float*)alloc((size_t)NC * 128 * 4);
    float* xeh    = (float*)alloc((size_t)NE * 128 * 4);
    size_t zbytes = off - zoff;

    hipMemsetAsync(base + zoff, 0, zbytes, stream);

    k_convW<<<(256 * 256 + 128 * 128 + 255) / 256, 256, 0, stream>>>(
        wh, wt, hww, wtb_hi, wtb_lo, hwt_hi, hwt_lo);
    k_rel<<<(NR + 3) / 4, 256, 0, stream>>>(remb, ar1, ar2, er1b, er2b, NR);

    int mblks = (NE + 127) / 128;
    k_gemm<256, 0><<<mblks * 2, 256, 0, stream>>>(xe, wtb_hi, wtb_lo, xrh, xrt,
                                                  nullptr, nullptr, NE, 1);
    k_dots<<<(NE + 3) / 4, 256, 0, stream>>>(xrh, xrt, ah1, ah2, ah3, ah4, at1, at2, at3,
                                             eh1, eh2, eh3, eh4, et1b, et2b, et3b, nrmb, NE);
    k_edge1<<<(E + 255) / 256, 256, 0, stream>>>(hidx, tidx, rel, tnum, eh1, et1b, er1b, zbuf, m1, E);
    k_edge2<<<(E + 255) / 256, 256, 0, stream>>>(tnum, zbuf, m1, s1, E);
    k_edge3<<<(E + 255) / 256, 256, 0, stream>>>(hidx, tidx, rel, tnum, cidx, zbuf, s1, nrmb,
                                                 eh2, eh3, et2b, et3b, er2b, sbuf, e2buf, m2, E);
    k_edge4<<<(E + 255) / 256, 256, 0, stream>>>(cidx, e2buf, m2, s2, E);
    k_spmm<<<2048, 256, 0, stream>>>(tidx, cidx, e2buf, s2, sbuf, xrt, xclass, E);
    k_class1<<<(NC + 3) / 4, 256, 0, stream>>>(xclass, ac, eh4, hcls, zc, m3, NC);
    k_class2<<<(NC + 255) / 256, 256, 0, stream>>>(hcls, zc, m3, s3, NC);
    k_class3<<<(NC + 3) / 4, 256, 0, stream>>>(hcls, zc, s3, xclass, xeh, NC);
    k_gemm<128, 1><<<mblks, 256, 0, stream>>>(xrh, hwt_hi, hwt_lo, out, nullptr,
                                              hwb, xeh, NE, 0);
}

// Round 3
// 732.310 us; speedup vs baseline: 2.0130x; 1.3493x over previous
//
#include <hip/hip_runtime.h>
#include <hip/hip_bf16.h>

#define LRELU(x) ((x) >= 0.f ? (x) : 0.01f * (x))

typedef __attribute__((ext_vector_type(8))) short short8v;
typedef __attribute__((ext_vector_type(4))) float f32x4;

__device__ inline unsigned fenc(float x) {
    unsigned u = __float_as_uint(x);
    return (u & 0x80000000u) ? ~u : (u | 0x80000000u);
}
__device__ inline float fdec(unsigned e) {
    return __uint_as_float((e & 0x80000000u) ? (e ^ 0x80000000u) : ~e);
}

__device__ inline float wred(float v) {
#pragma unroll
    for (int o = 32; o > 0; o >>= 1) v += __shfl_xor(v, o, 64);
    return v;
}
__device__ inline float wredmax(float v) {
#pragma unroll
    for (int o = 32; o > 0; o >>= 1) v = fmaxf(v, __shfl_xor(v, o, 64));
    return v;
}

__device__ inline unsigned short f2bu(float x) {
    __hip_bfloat16 b = __float2bfloat16(x);
    return *reinterpret_cast<unsigned short*>(&b);
}
__device__ inline float bu2f(unsigned short u) {
    return __uint_as_float((unsigned)u << 16);
}

__device__ inline f32x4 mfma16(short8v a, short8v b, f32x4 c) {
    return __builtin_amdgcn_mfma_f32_16x16x32_bf16(a, b, c, 0, 0, 0);
}

// ---- convert W matrices to transposed hi/lo bf16: Wt[n][k] = W[k][n] ----
__global__ __launch_bounds__(256) void k_convW(
    const float* __restrict__ wh, const float* __restrict__ wt,
    const float* __restrict__ hww, unsigned short* __restrict__ wtb_hi,
    unsigned short* __restrict__ wtb_lo, unsigned short* __restrict__ hwt_hi,
    unsigned short* __restrict__ hwt_lo) {
    int id = blockIdx.x * 256 + threadIdx.x;
    if (id < 256 * 256) {
        int n = id >> 8, k = id & 255;
        float v = (n < 128) ? wh[(size_t)k * 128 + n] : wt[(size_t)k * 128 + (n - 128)];
        unsigned short h = f2bu(v);
        float r = v - bu2f(h);
        wtb_hi[(size_t)n * 256 + k] = h;
        wtb_lo[(size_t)n * 256 + k] = f2bu(r);
    } else {
        int id2 = id - 256 * 256;
        if (id2 < 128 * 128) {
            int n = id2 >> 7, k = id2 & 127;
            float v = hww[(size_t)k * 128 + n];
            unsigned short h = f2bu(v);
            float r = v - bu2f(h);
            hwt_hi[(size_t)n * 128 + k] = h;
            hwt_lo[(size_t)n * 128 + k] = f2bu(r);
        }
    }
}

// ---- split-bf16 MFMA GEMM ----
template <int KD, int EPI>
__global__ __launch_bounds__(256) void k_gemm(
    const float* __restrict__ A, const unsigned short* __restrict__ Bh,
    const unsigned short* __restrict__ Bl, float* __restrict__ o0,
    float* __restrict__ o1, const float* __restrict__ bias,
    const float* __restrict__ xeh, int M, int nBlk2) {
    int bx = blockIdx.x;
    int mblk = nBlk2 ? (bx >> 1) : bx;
    int n0 = nBlk2 ? ((bx & 1) << 7) : 0;
    int row0 = mblk * 128;
    if (row0 + 128 > M) row0 = M - 128;
    int tid = threadIdx.x;
    int w = tid >> 6, l = tid & 63;
    int lr = l & 15;
    int lk = (l >> 4) * 8;

    f32x4 acc[2][8];
#pragma unroll
    for (int i = 0; i < 2; i++)
#pragma unroll
        for (int j = 0; j < 8; j++) acc[i][j] = (f32x4){0.f, 0.f, 0.f, 0.f};

    const float* ap0 = A + (size_t)(row0 + w * 32 + lr) * KD + lk;
    const float* ap1 = ap0 + (size_t)16 * KD;
    const unsigned short* bp_h = Bh + (size_t)(n0 + lr) * KD + lk;
    const unsigned short* bp_l = Bl + (size_t)(n0 + lr) * KD + lk;

    for (int k0 = 0; k0 < KD; k0 += 32) {
        short8v ah[2], al[2];
#pragma unroll
        for (int rf = 0; rf < 2; rf++) {
            const float* ap = (rf ? ap1 : ap0) + k0;
            float4 xa = *(const float4*)ap;
            float4 xb = *(const float4*)(ap + 4);
            float xs[8] = {xa.x, xa.y, xa.z, xa.w, xb.x, xb.y, xb.z, xb.w};
#pragma unroll
            for (int j = 0; j < 8; j++) {
                unsigned short hu = f2bu(xs[j]);
                ah[rf][j] = (short)hu;
                al[rf][j] = (short)f2bu(xs[j] - bu2f(hu));
            }
        }
#pragma unroll
        for (int cf = 0; cf < 8; cf++) {
            const unsigned short* bph = bp_h + (size_t)(cf * 16) * KD + k0;
            const unsigned short* bpl = bp_l + (size_t)(cf * 16) * KD + k0;
            short8v bh = *(const short8v*)bph;
            short8v bl = *(const short8v*)bpl;
#pragma unroll
            for (int rf = 0; rf < 2; rf++) {
                acc[rf][cf] = mfma16(ah[rf], bh, acc[rf][cf]);
                acc[rf][cf] = mfma16(al[rf], bh, acc[rf][cf]);
                acc[rf][cf] = mfma16(ah[rf], bl, acc[rf][cf]);
            }
        }
    }

    if (EPI == 0) {
        float* O = n0 ? o1 : o0;
#pragma unroll
        for (int rf = 0; rf < 2; rf++)
#pragma unroll
            for (int cf = 0; cf < 8; cf++)
#pragma unroll
                for (int r = 0; r < 4; r++) {
                    int row = row0 + w * 32 + rf * 16 + (l >> 4) * 4 + r;
                    int col = cf * 16 + lr;
                    O[(size_t)row * 128 + col] = fmaxf(acc[rf][cf][r], 0.f);
                }
    } else {
#pragma unroll
        for (int rf = 0; rf < 2; rf++)
#pragma unroll
            for (int cf = 0; cf < 8; cf++)
#pragma unroll
                for (int r = 0; r < 4; r++) {
                    int row = row0 + w * 32 + rf * 16 + (l >> 4) * 4 + r;
                    int col = cf * 16 + lr;
                    float a = acc[rf][cf][r] + bias[col];
                    float g = 1.f / (1.f + expf(-a));
                    size_t o = (size_t)row * 128 + col;
                    o0[o] = g * xeh[o] + (1.f - g) * A[o];
                }
    }
}

// ---- relation dots ----
__global__ __launch_bounds__(256) void k_rel(const float* __restrict__ remb,
                                             const float* __restrict__ ar1,
                                             const float* __restrict__ ar2,
                                             float* __restrict__ er1,
                                             float* __restrict__ er2, int NR) {
    int lane = threadIdx.x & 63;
    int r = blockIdx.x * 4 + (threadIdx.x >> 6);
    if (r >= NR) return;
    float v0 = remb[(size_t)r * 128 + lane];
    float v1 = remb[(size_t)r * 128 + 64 + lane];
    float p1 = v0 * ar1[lane] + v1 * ar1[64 + lane];
    float p2 = v0 * ar2[lane] + v1 * ar2[64 + lane];
    p1 = wred(p1);
    p2 = wred(p2);
    if (lane == 0) { er1[r] = p1; er2[r] = p2; }
}

// ---- per-entity scalar dots + ||x_r_t|| ----
__global__ __launch_bounds__(256) void k_dots(
    const float* __restrict__ xrh, const float* __restrict__ xrt,
    const float* __restrict__ ah1, const float* __restrict__ ah2,
    const float* __restrict__ ah3, const float* __restrict__ ah4,
    const float* __restrict__ at1, const float* __restrict__ at2,
    const float* __restrict__ at3, float* __restrict__ o_eh1,
    float* __restrict__ o_eh2, float* __restrict__ o_eh3,
    float* __restrict__ o_eh4, float* __restrict__ o_et1,
    float* __restrict__ o_et2, float* __restrict__ o_et3,
    float* __restrict__ o_nrm, int NE) {
    int lane = threadIdx.x & 63;
    int n = blockIdx.x * 4 + (threadIdx.x >> 6);
    if (n >= NE) return;
    float h0 = xrh[(size_t)n * 128 + lane], h1 = xrh[(size_t)n * 128 + 64 + lane];
    float t0 = xrt[(size_t)n * 128 + lane], t1 = xrt[(size_t)n * 128 + 64 + lane];
    float p;
    p = wred(h0 * ah1[lane] + h1 * ah1[64 + lane]); if (!lane) o_eh1[n] = p;
    p = wred(h0 * ah2[lane] + h1 * ah2[64 + lane]); if (!lane) o_eh2[n] = p;
    p = wred(h0 * ah3[lane] + h1 * ah3[64 + lane]); if (!lane) o_eh3[n] = p;
    p = wred(h0 * ah4[lane] + h1 * ah4[64 + lane]); if (!lane) o_eh4[n] = p;
    p = wred(t0 * at1[lane] + t1 * at1[64 + lane]); if (!lane) o_et1[n] = p;
    p = wred(t0 * at2[lane] + t1 * at2[64 + lane]); if (!lane) o_et2[n] = p;
    p = wred(t0 * at3[lane] + t1 * at3[64 + lane]); if (!lane) o_et3[n] = p;
    p = wred(t0 * t0 + t1 * t1);                    if (!lane) o_nrm[n] = sqrtf(p);
}

// ---- level 1 softmax over triple_num segments ----
__global__ __launch_bounds__(256) void k_edge1(
    const int* __restrict__ hidx, const int* __restrict__ tidx,
    const int* __restrict__ rel, const int* __restrict__ tnum,
    const float* __restrict__ eh1, const float* __restrict__ et1,
    const float* __restrict__ er1, float* __restrict__ zbuf,
    unsigned* __restrict__ m1, int E) {
    int i = blockIdx.x * 256 + threadIdx.x;
    if (i >= E) return;
    float e1 = 0.5f * (eh1[hidx[i]] + et1[tidx[i]]) + er1[rel[i]];
    float z = LRELU(e1);
    zbuf[i] = z;
    atomicMax(&m1[tnum[i]], fenc(z));
}

__global__ __launch_bounds__(256) void k_edge2(const int* __restrict__ tnum,
                                               float* __restrict__ zbuf,
                                               const unsigned* __restrict__ m1,
                                               float* __restrict__ s1, int E) {
    int i = blockIdx.x * 256 + threadIdx.x;
    if (i >= E) return;
    int tn = tnum[i];
    float ex = expf(zbuf[i] - fdec(m1[tn]));
    zbuf[i] = ex;
    atomicAdd(&s1[tn], ex);
}

// ---- alpha -> per-edge scale s, level-2 logit z2 (no atomics) ----
__global__ __launch_bounds__(256) void k_edge3(
    const int* __restrict__ hidx, const int* __restrict__ tidx,
    const int* __restrict__ rel, const int* __restrict__ tnum,
    const float* __restrict__ zbuf, const float* __restrict__ s1,
    const float* __restrict__ nrm, const float* __restrict__ eh2,
    const float* __restrict__ eh3, const float* __restrict__ et2,
    const float* __restrict__ et3, const float* __restrict__ er2,
    float* __restrict__ sbuf, float* __restrict__ e2buf, int E) {
    int i = blockIdx.x * 256 + threadIdx.x;
    if (i >= E) return;
    float alpha = zbuf[i] / (s1[tnum[i]] + 1e-16f);
    int t = tidx[i];
    float s = alpha / fmaxf(alpha * nrm[t], 1e-12f);
    sbuf[i] = s;
    int h = hidx[i];
    float z2 = s * et2[t] + eh2[h] + 0.5f * (er2[rel[i]] + 0.5f * (eh3[h] + s * et3[t]));
    e2buf[i] = LRELU(z2);
}

// ---- counting sort by class_index ----
__global__ __launch_bounds__(256) void k_hist(const int* __restrict__ cidx,
                                              int* __restrict__ cnt, int E) {
    int i = blockIdx.x * 256 + threadIdx.x;
    if (i >= E) return;
    atomicAdd(&cnt[cidx[i]], 1);
}

__global__ __launch_bounds__(1024) void k_scan(const int* __restrict__ cnt,
                                               int* __restrict__ off,
                                               int* __restrict__ cur, int NC) {
    __shared__ int wt[16];
    __shared__ int sbase;
    int tid = threadIdx.x, w = tid >> 6, lane = tid & 63;
    if (tid == 0) sbase = 0;
    __syncthreads();
    for (int c0 = 0; c0 < NC; c0 += 1024) {
        int c = c0 + tid;
        int v = (c < NC) ? cnt[c] : 0;
        int x = v;
#pragma unroll
        for (int o = 1; o < 64; o <<= 1) {
            int t = __shfl_up(x, o, 64);
            if (lane >= o) x += t;
        }
        if (lane == 63) wt[w] = x;
        __syncthreads();
        int pre = 0, tot = 0;
#pragma unroll
        for (int i = 0; i < 16; i++) {
            int t = wt[i];
            tot += t;
            if (i < w) pre += t;
        }
        int excl = sbase + pre + x - v;
        if (c < NC) { off[c] = excl; cur[c] = excl; }
        __syncthreads();
        if (tid == 0) sbase += tot;
        __syncthreads();
    }
}

__global__ __launch_bounds__(256) void k_scatter(const int* __restrict__ cidx,
                                                 int* __restrict__ cur,
                                                 int* __restrict__ elist, int E) {
    int i = blockIdx.x * 256 + threadIdx.x;
    if (i >= E) return;
    int pos = atomicAdd(&cur[cidx[i]], 1);
    elist[pos] = i;
}

// ---- fused level-2 softmax + spmm, one wave per class, no atomics ----
__global__ __launch_bounds__(256) void k_spmm2(
    const int* __restrict__ elist, const int* __restrict__ off,
    const int* __restrict__ cnt, const int* __restrict__ tidx,
    const float* __restrict__ e2buf, const float* __restrict__ sbuf,
    const float* __restrict__ xrt, float* __restrict__ xclass, int NC) {
    int lane = threadIdx.x & 63;
    int c = blockIdx.x * 4 + (threadIdx.x >> 6);
    if (c >= NC) return;
    int n = cnt[c];
    if (n == 0) {
        xclass[(size_t)c * 128 + lane] = 0.f;
        xclass[(size_t)c * 128 + 64 + lane] = 0.f;
        return;
    }
    int base = off[c];
    // pass A: segment max and exp-sum
    float m = -3.4e38f;
    for (int j = lane; j < n; j += 64) m = fmaxf(m, e2buf[elist[base + j]]);
    m = wredmax(m);
    float s = 0.f;
    for (int j = lane; j < n; j += 64) s += expf(e2buf[elist[base + j]] - m);
    s = wred(s);
    float inv = 1.f / (s + 1e-16f);
    // pass B: weighted row accumulation
    float a0 = 0.f, a1 = 0.f;
    for (int j0 = 0; j0 < n; j0 += 64) {
        int lim = n - j0;
        if (lim > 64) lim = 64;
        float wv = 0.f;
        int g = 0;
        if (lane < lim) {
            int e = elist[base + j0 + lane];
            wv = expf(e2buf[e] - m) * inv;
            int te = tidx[e];
            wv *= sbuf[te];
            g = tidx[te];
        }
        for (int jj = 0; jj < lim; jj++) {
            float wj = __shfl(wv, jj);
            int gj = __shfl(g, jj);
            a0 = fmaf(wj, xrt[(size_t)gj * 128 + lane], a0);
            a1 = fmaf(wj, xrt[(size_t)gj * 128 + 64 + lane], a1);
        }
    }
    xclass[(size_t)c * 128 + lane] = a0;
    xclass[(size_t)c * 128 + 64 + lane] = a1;
}

// ---- level 3: class -> head entity ----
__global__ __launch_bounds__(256) void k_class1(
    const float* __restrict__ xclass, const float* __restrict__ ac,
    const float* __restrict__ eh4, const int* __restrict__ hclass,
    float* __restrict__ zc, unsigned* __restrict__ m3, int NC) {
    int lane = threadIdx.x & 63;
    int c = blockIdx.x * 4 + (threadIdx.x >> 6);
    if (c >= NC) return;
    float v0 = xclass[(size_t)c * 128 + lane], v1 = xclass[(size_t)c * 128 + 64 + lane];
    float p = wred(v0 * ac[lane] + v1 * ac[64 + lane]);
    if (lane == 0) {
        int hc = hclass[c];
        float z = LRELU(p + eh4[hc]);
        zc[c] = z;
        atomicMax(&m3[hc], fenc(z));
    }
}

__global__ __launch_bounds__(256) void k_class2(const int* __restrict__ hclass,
                                                float* __restrict__ zc,
                                                const unsigned* __restrict__ m3,
                                                float* __restrict__ s3, int NC) {
    int c = blockIdx.x * 256 + threadIdx.x;
    if (c >= NC) return;
    int hc = hclass[c];
    float ex = expf(zc[c] - fdec(m3[hc]));
    zc[c] = ex;
    atomicAdd(&s3[hc], ex);
}

__global__ __launch_bounds__(256) void k_class3(
    const int* __restrict__ hclass, const float* __restrict__ zc,
    const float* __restrict__ s3, const float* __restrict__ xclass,
    float* __restrict__ xeh, int NC) {
    int lane = threadIdx.x & 63;
    int c = blockIdx.x * 4 + (threadIdx.x >> 6);
    if (c >= NC) return;
    int hc = hclass[c];
    float gama = zc[c] / (s3[hc] + 1e-16f);
    float v0 = xclass[(size_t)c * 128 + lane], v1 = xclass[(size_t)c * 128 + 64 + lane];
    atomicAdd(&xeh[(size_t)hc * 128 + lane], gama * v0);
    atomicAdd(&xeh[(size_t)hc * 128 + 64 + lane], gama * v1);
}

extern "C" void kernel_launch(void* const* d_in, const int* in_sizes, int n_in,
                              void* d_out, int out_size, void* d_ws, size_t ws_size,
                              hipStream_t stream) {
    (void)n_in; (void)out_size; (void)ws_size;
    const float* xe   = (const float*)d_in[0];
    const int*   eidx = (const int*)d_in[1];
    const int*   rel  = (const int*)d_in[2];
    const int*   tnum = (const int*)d_in[3];
    const float* remb = (const float*)d_in[4];
    const int*   cidx = (const int*)d_in[5];
    const int*   hcls = (const int*)d_in[6];
    const float* ah1  = (const float*)d_in[7];
    const float* ah2  = (const float*)d_in[8];
    const float* ah3  = (const float*)d_in[9];
    const float* ah4  = (const float*)d_in[10];
    const float* at1  = (const float*)d_in[11];
    const float* at2  = (const float*)d_in[12];
    const float* at3  = (const float*)d_in[13];
    const float* ar1  = (const float*)d_in[14];
    const float* ar2  = (const float*)d_in[15];
    const float* ac   = (const float*)d_in[16];
    const float* wh   = (const float*)d_in[17];
    const float* wt   = (const float*)d_in[18];
    const float* hww  = (const float*)d_in[19];
    const float* hwb  = (const float*)d_in[20];
    float* out = (float*)d_out;

    const int NE = in_sizes[0] / 256;
    const int E  = in_sizes[2];
    const int NR = in_sizes[4] / 128;
    const int NC = in_sizes[6];
    const int* hidx = eidx;
    const int* tidx = eidx + E;

    char* base = (char*)d_ws;
    size_t off0 = 0;
    auto alloc = [&](size_t bytes) -> char* {
        char* r = base + off0;
        off0 = (off0 + bytes + 255) & ~(size_t)255;
        return r;
    };
    float* xrh  = (float*)alloc((size_t)NE * 128 * 4);
    float* xrt  = (float*)alloc((size_t)NE * 128 * 4);
    float* eh1  = (float*)alloc((size_t)NE * 4);
    float* eh2  = (float*)alloc((size_t)NE * 4);
    float* eh3  = (float*)alloc((size_t)NE * 4);
    float* eh4  = (float*)alloc((size_t)NE * 4);
    float* et1b = (float*)alloc((size_t)NE * 4);
    float* et2b = (float*)alloc((size_t)NE * 4);
    float* et3b = (float*)alloc((size_t)NE * 4);
    float* nrmb = (float*)alloc((size_t)NE * 4);
    float* er1b = (float*)alloc((size_t)NR * 4);
    float* er2b = (float*)alloc((size_t)NR * 4);
    float* zbuf  = (float*)alloc((size_t)E * 4);
    float* e2buf = (float*)alloc((size_t)E * 4);
    float* sbuf  = (float*)alloc((size_t)E * 4);
    float* zc    = (float*)alloc((size_t)NC * 4);
    unsigned short* wtb_hi = (unsigned short*)alloc((size_t)256 * 256 * 2);
    unsigned short* wtb_lo = (unsigned short*)alloc((size_t)256 * 256 * 2);
    unsigned short* hwt_hi = (unsigned short*)alloc((size_t)128 * 128 * 2);
    unsigned short* hwt_lo = (unsigned short*)alloc((size_t)128 * 128 * 2);
    int* offb  = (int*)alloc((size_t)NC * 4);
    int* curb  = (int*)alloc((size_t)NC * 4);
    int* elist = (int*)alloc((size_t)E * 4);
    float* xclass = (float*)alloc((size_t)NC * 128 * 4);
    size_t zoff = off0;  // everything below is zero-initialized per launch
    unsigned* m1 = (unsigned*)alloc((size_t)NE * 4);
    float* s1    = (float*)alloc((size_t)NE * 4);
    unsigned* m3 = (unsigned*)alloc((size_t)NE * 4);
    float* s3    = (float*)alloc((size_t)NE * 4);
    int* cntb    = (int*)alloc((size_t)NC * 4);
    float* xeh   = (float*)alloc((size_t)NE * 128 * 4);
    size_t zbytes = off0 - zoff;

    hipMemsetAsync(base + zoff, 0, zbytes, stream);

    k_convW<<<(256 * 256 + 128 * 128 + 255) / 256, 256, 0, stream>>>(
        wh, wt, hww, wtb_hi, wtb_lo, hwt_hi, hwt_lo);
    k_rel<<<(NR + 3) / 4, 256, 0, stream>>>(remb, ar1, ar2, er1b, er2b, NR);

    int mblks = (NE + 127) / 128;
    k_gemm<256, 0><<<mblks * 2, 256, 0, stream>>>(xe, wtb_hi, wtb_lo, xrh, xrt,
                                                  nullptr, nullptr, NE, 1);
    k_dots<<<(NE + 3) / 4, 256, 0, stream>>>(xrh, xrt, ah1, ah2, ah3, ah4, at1, at2, at3,
                                             eh1, eh2, eh3, eh4, et1b, et2b, et3b, nrmb, NE);
    // class-CSR build (independent of edge kernels)
    k_hist<<<(E + 255) / 256, 256, 0, stream>>>(cidx, cntb, E);
    k_scan<<<1, 1024, 0, stream>>>(cntb, offb, curb, NC);
    k_scatter<<<(E + 255) / 256, 256, 0, stream>>>(cidx, curb, elist, E);

    k_edge1<<<(E + 255) / 256, 256, 0, stream>>>(hidx, tidx, rel, tnum, eh1, et1b, er1b, zbuf, m1, E);
    k_edge2<<<(E + 255) / 256, 256, 0, stream>>>(tnum, zbuf, m1, s1, E);
    k_edge3<<<(E + 255) / 256, 256, 0, stream>>>(hidx, tidx, rel, tnum, zbuf, s1, nrmb,
                                                 eh2, eh3, et2b, et3b, er2b, sbuf, e2buf, E);
    k_spmm2<<<(NC + 3) / 4, 256, 0, stream>>>(elist, offb, cntb, tidx, e2buf, sbuf,
                                              xrt, xclass, NC);
    k_class1<<<(NC + 3) / 4, 256, 0, stream>>>(xclass, ac, eh4, hcls, zc, m3, NC);
    k_class2<<<(NC + 255) / 256, 256, 0, stream>>>(hcls, zc, m3, s3, NC);
    k_class3<<<(NC + 3) / 4, 256, 0, stream>>>(hcls, zc, s3, xclass, xeh, NC);
    k_gemm<128, 1><<<mblks, 256, 0, stream>>>(xrh, hwt_hi, hwt_lo, out, nullptr,
                                              hwb, xeh, NE, 0);
}

// Round 4
// 670.390 us; speedup vs baseline: 2.1989x; 1.0924x over previous
//
#include <hip/hip_runtime.h>
#include <hip/hip_bf16.h>

#define LRELU(x) ((x) >= 0.f ? (x) : 0.01f * (x))

typedef __attribute__((ext_vector_type(8))) short short8v;
typedef __attribute__((ext_vector_type(4))) float f32x4;

__device__ inline unsigned fenc(float x) {
    unsigned u = __float_as_uint(x);
    return (u & 0x80000000u) ? ~u : (u | 0x80000000u);
}
__device__ inline float fdec(unsigned e) {
    return __uint_as_float((e & 0x80000000u) ? (e ^ 0x80000000u) : ~e);
}

__device__ inline float wred(float v) {
#pragma unroll
    for (int o = 32; o > 0; o >>= 1) v += __shfl_xor(v, o, 64);
    return v;
}
__device__ inline float wredmax(float v) {
#pragma unroll
    for (int o = 32; o > 0; o >>= 1) v = fmaxf(v, __shfl_xor(v, o, 64));
    return v;
}

__device__ inline unsigned short f2bu(float x) {
    __hip_bfloat16 b = __float2bfloat16(x);
    return *reinterpret_cast<unsigned short*>(&b);
}
__device__ inline float bu2f(unsigned short u) {
    return __uint_as_float((unsigned)u << 16);
}

__device__ inline f32x4 mfma16(short8v a, short8v b, f32x4 c) {
    return __builtin_amdgcn_mfma_f32_16x16x32_bf16(a, b, c, 0, 0, 0);
}

// ---- convert W matrices to transposed hi/lo bf16: Wt[n][k] = W[k][n] ----
__global__ __launch_bounds__(256) void k_convW(
    const float* __restrict__ wh, const float* __restrict__ wt,
    const float* __restrict__ hww, unsigned short* __restrict__ wtb_hi,
    unsigned short* __restrict__ wtb_lo, unsigned short* __restrict__ hwt_hi,
    unsigned short* __restrict__ hwt_lo) {
    int id = blockIdx.x * 256 + threadIdx.x;
    if (id < 256 * 256) {
        int n = id >> 8, k = id & 255;
        float v = (n < 128) ? wh[(size_t)k * 128 + n] : wt[(size_t)k * 128 + (n - 128)];
        unsigned short h = f2bu(v);
        float r = v - bu2f(h);
        wtb_hi[(size_t)n * 256 + k] = h;
        wtb_lo[(size_t)n * 256 + k] = f2bu(r);
    } else {
        int id2 = id - 256 * 256;
        if (id2 < 128 * 128) {
            int n = id2 >> 7, k = id2 & 127;
            float v = hww[(size_t)k * 128 + n];
            unsigned short h = f2bu(v);
            float r = v - bu2f(h);
            hwt_hi[(size_t)n * 128 + k] = h;
            hwt_lo[(size_t)n * 128 + k] = f2bu(r);
        }
    }
}

// ---- split-bf16 MFMA GEMM with depth-1 A prefetch ----
// EPI 0 (proj, KD=256): 4 waves = 2 rowgroups x 2 col-halves; BM=64.
//   ch=0 -> relu -> o0 (xrh) + dots {av1..av4 -> d1o..d4o}
//   ch=1 -> relu -> o1 (xrt) + dots {bv1..bv3 -> e1o..e3o} + norm -> nrmo
// EPI 1 (highway, KD=128): 4 waves = 4 rowgroups; BM=128; N=128.
//   gate = sigmoid(C + bias); o0 = gate*xeh + (1-gate)*A
template <int KD, int EPI>
__global__ __launch_bounds__(256) void k_gemm(
    const float* __restrict__ A, const unsigned short* __restrict__ Bh,
    const unsigned short* __restrict__ Bl, float* __restrict__ o0,
    float* __restrict__ o1, const float* __restrict__ bias,
    const float* __restrict__ xeh, int M,
    const float* __restrict__ av1, const float* __restrict__ av2,
    const float* __restrict__ av3, const float* __restrict__ av4,
    const float* __restrict__ bv1, const float* __restrict__ bv2,
    const float* __restrict__ bv3, float* __restrict__ d1o,
    float* __restrict__ d2o, float* __restrict__ d3o, float* __restrict__ d4o,
    float* __restrict__ e1o, float* __restrict__ e2o, float* __restrict__ e3o,
    float* __restrict__ nrmo) {
    constexpr int NH = (EPI == 0) ? 2 : 1;   // col halves
    constexpr int RG = 4 / NH;               // row groups
    constexpr int BM = RG * 32;
    int row0 = blockIdx.x * BM;
    if (row0 + BM > M) row0 = M - BM;
    int tid = threadIdx.x;
    int w = tid >> 6, l = tid & 63;
    int rg = w & (RG - 1), ch = w / RG;
    int lr = l & 15, hi4 = l >> 4;
    int lk = hi4 * 8;

    f32x4 acc[2][8];
#pragma unroll
    for (int i = 0; i < 2; i++)
#pragma unroll
        for (int j = 0; j < 8; j++) acc[i][j] = (f32x4){0.f, 0.f, 0.f, 0.f};

    const float* ap0 = A + (size_t)(row0 + rg * 32 + lr) * KD + lk;
    const float* ap1 = ap0 + (size_t)16 * KD;
    const unsigned short* bp_h = Bh + (size_t)(ch * 128 + lr) * KD + lk;
    const unsigned short* bp_l = Bl + (size_t)(ch * 128 + lr) * KD + lk;

    float4 nx[2][2];
    nx[0][0] = *(const float4*)ap0;
    nx[0][1] = *(const float4*)(ap0 + 4);
    nx[1][0] = *(const float4*)ap1;
    nx[1][1] = *(const float4*)(ap1 + 4);

    for (int k0 = 0; k0 < KD; k0 += 32) {
        float4 cx[2][2];
        cx[0][0] = nx[0][0]; cx[0][1] = nx[0][1];
        cx[1][0] = nx[1][0]; cx[1][1] = nx[1][1];
        if (k0 + 32 < KD) {  // prefetch next A tile before the MFMA phase
            nx[0][0] = *(const float4*)(ap0 + k0 + 32);
            nx[0][1] = *(const float4*)(ap0 + k0 + 36);
            nx[1][0] = *(const float4*)(ap1 + k0 + 32);
            nx[1][1] = *(const float4*)(ap1 + k0 + 36);
        }
        short8v ah[2], al[2];
#pragma unroll
        for (int rf = 0; rf < 2; rf++) {
            float xs[8] = {cx[rf][0].x, cx[rf][0].y, cx[rf][0].z, cx[rf][0].w,
                           cx[rf][1].x, cx[rf][1].y, cx[rf][1].z, cx[rf][1].w};
#pragma unroll
            for (int j = 0; j < 8; j++) {
                unsigned short hu = f2bu(xs[j]);
                ah[rf][j] = (short)hu;
                al[rf][j] = (short)f2bu(xs[j] - bu2f(hu));
            }
        }
#pragma unroll
        for (int cf = 0; cf < 8; cf++) {
            short8v bh = *(const short8v*)(bp_h + (size_t)(cf * 16) * KD + k0);
            short8v bl = *(const short8v*)(bp_l + (size_t)(cf * 16) * KD + k0);
#pragma unroll
            for (int rf = 0; rf < 2; rf++) {
                acc[rf][cf] = mfma16(ah[rf], bh, acc[rf][cf]);
                acc[rf][cf] = mfma16(al[rf], bh, acc[rf][cf]);
                acc[rf][cf] = mfma16(ah[rf], bl, acc[rf][cf]);
            }
        }
    }

    if (EPI == 0) {
        float* O = ch ? o1 : o0;
        const float* v1 = ch ? bv1 : av1;
        const float* v2 = ch ? bv2 : av2;
        const float* v3 = ch ? bv3 : av3;
#pragma unroll
        for (int rf = 0; rf < 2; rf++)
#pragma unroll
            for (int r = 0; r < 4; r++) {
                int row = row0 + rg * 32 + rf * 16 + hi4 * 4 + r;
                float d1 = 0.f, d2 = 0.f, d3 = 0.f, d4 = 0.f;
#pragma unroll
                for (int cf = 0; cf < 8; cf++) {
                    float v = fmaxf(acc[rf][cf][r], 0.f);
                    int col = cf * 16 + lr;
                    O[(size_t)row * 128 + col] = v;
                    d1 = fmaf(v, v1[col], d1);
                    d2 = fmaf(v, v2[col], d2);
                    d3 = fmaf(v, v3[col], d3);
                    d4 = fmaf(v, ch ? v : av4[col], d4);
                }
#pragma unroll
                for (int o = 1; o <= 8; o <<= 1) {
                    d1 += __shfl_xor(d1, o, 64);
                    d2 += __shfl_xor(d2, o, 64);
                    d3 += __shfl_xor(d3, o, 64);
                    d4 += __shfl_xor(d4, o, 64);
                }
                if (lr == 0) {
                    if (ch == 0) {
                        d1o[row] = d1; d2o[row] = d2; d3o[row] = d3; d4o[row] = d4;
                    } else {
                        e1o[row] = d1; e2o[row] = d2; e3o[row] = d3;
                        nrmo[row] = sqrtf(d4);
                    }
                }
            }
    } else {
#pragma unroll
        for (int rf = 0; rf < 2; rf++)
#pragma unroll
            for (int cf = 0; cf < 8; cf++)
#pragma unroll
                for (int r = 0; r < 4; r++) {
                    int row = row0 + rg * 32 + rf * 16 + hi4 * 4 + r;
                    int col = cf * 16 + lr;
                    float a = acc[rf][cf][r] + bias[col];
                    float g = 1.f / (1.f + expf(-a));
                    size_t o = (size_t)row * 128 + col;
                    o0[o] = g * xeh[o] + (1.f - g) * A[o];
                }
    }
}

// ---- relation dots ----
__global__ __launch_bounds__(256) void k_rel(const float* __restrict__ remb,
                                             const float* __restrict__ ar1,
                                             const float* __restrict__ ar2,
                                             float* __restrict__ er1,
                                             float* __restrict__ er2, int NR) {
    int lane = threadIdx.x & 63;
    int r = blockIdx.x * 4 + (threadIdx.x >> 6);
    if (r >= NR) return;
    float v0 = remb[(size_t)r * 128 + lane];
    float v1 = remb[(size_t)r * 128 + 64 + lane];
    float p1 = v0 * ar1[lane] + v1 * ar1[64 + lane];
    float p2 = v0 * ar2[lane] + v1 * ar2[64 + lane];
    p1 = wred(p1);
    p2 = wred(p2);
    if (lane == 0) { er1[r] = p1; er2[r] = p2; }
}

// ---- level 1 softmax over triple_num segments ----
__global__ __launch_bounds__(256) void k_edge1(
    const int* __restrict__ hidx, const int* __restrict__ tidx,
    const int* __restrict__ rel, const int* __restrict__ tnum,
    const float* __restrict__ eh1, const float* __restrict__ et1,
    const float* __restrict__ er1, float* __restrict__ zbuf,
    unsigned* __restrict__ m1, int E) {
    int i = blockIdx.x * 256 + threadIdx.x;
    if (i >= E) return;
    float e1 = 0.5f * (eh1[hidx[i]] + et1[tidx[i]]) + er1[rel[i]];
    float z = LRELU(e1);
    zbuf[i] = z;
    atomicMax(&m1[tnum[i]], fenc(z));
}

__global__ __launch_bounds__(256) void k_edge2(const int* __restrict__ tnum,
                                               float* __restrict__ zbuf,
                                               const unsigned* __restrict__ m1,
                                               float* __restrict__ s1, int E) {
    int i = blockIdx.x * 256 + threadIdx.x;
    if (i >= E) return;
    int tn = tnum[i];
    float ex = expf(zbuf[i] - fdec(m1[tn]));
    zbuf[i] = ex;
    atomicAdd(&s1[tn], ex);
}

// ---- alpha -> per-edge scale s, level-2 logit z2 (no atomics) ----
__global__ __launch_bounds__(256) void k_edge3(
    const int* __restrict__ hidx, const int* __restrict__ tidx,
    const int* __restrict__ rel, const int* __restrict__ tnum,
    const float* __restrict__ zbuf, const float* __restrict__ s1,
    const float* __restrict__ nrm, const float* __restrict__ eh2,
    const float* __restrict__ eh3, const float* __restrict__ et2,
    const float* __restrict__ et3, const float* __restrict__ er2,
    float* __restrict__ sbuf, float* __restrict__ e2buf, int E) {
    int i = blockIdx.x * 256 + threadIdx.x;
    if (i >= E) return;
    float alpha = zbuf[i] / (s1[tnum[i]] + 1e-16f);
    int t = tidx[i];
    float s = alpha / fmaxf(alpha * nrm[t], 1e-12f);
    sbuf[i] = s;
    int h = hidx[i];
    float z2 = s * et2[t] + eh2[h] + 0.5f * (er2[rel[i]] + 0.5f * (eh3[h] + s * et3[t]));
    e2buf[i] = LRELU(z2);
}

// ---- counting sort by class_index ----
__global__ __launch_bounds__(256) void k_hist(const int* __restrict__ cidx,
                                              int* __restrict__ cnt, int E) {
    int i = blockIdx.x * 256 + threadIdx.x;
    if (i >= E) return;
    atomicAdd(&cnt[cidx[i]], 1);
}

__global__ __launch_bounds__(1024) void k_scan(const int* __restrict__ cnt,
                                               int* __restrict__ off,
                                               int* __restrict__ cur, int NC) {
    __shared__ int wt[16];
    __shared__ int sbase;
    int tid = threadIdx.x, w = tid >> 6, lane = tid & 63;
    if (tid == 0) sbase = 0;
    __syncthreads();
    for (int c0 = 0; c0 < NC; c0 += 1024) {
        int c = c0 + tid;
        int v = (c < NC) ? cnt[c] : 0;
        int x = v;
#pragma unroll
        for (int o = 1; o < 64; o <<= 1) {
            int t = __shfl_up(x, o, 64);
            if (lane >= o) x += t;
        }
        if (lane == 63) wt[w] = x;
        __syncthreads();
        int pre = 0, tot = 0;
#pragma unroll
        for (int i = 0; i < 16; i++) {
            int t = wt[i];
            tot += t;
            if (i < w) pre += t;
        }
        int excl = sbase + pre + x - v;
        if (c < NC) { off[c] = excl; cur[c] = excl; }
        __syncthreads();
        if (tid == 0) sbase += tot;
        __syncthreads();
    }
}

__global__ __launch_bounds__(256) void k_scatter(const int* __restrict__ cidx,
                                                 int* __restrict__ cur,
                                                 int* __restrict__ elist, int E) {
    int i = blockIdx.x * 256 + threadIdx.x;
    if (i >= E) return;
    int pos = atomicAdd(&cur[cidx[i]], 1);
    elist[pos] = i;
}

// ---- fused level-2 softmax + spmm, one wave per class, no atomics ----
__global__ __launch_bounds__(256) void k_spmm2(
    const int* __restrict__ elist, const int* __restrict__ off,
    const int* __restrict__ cnt, const int* __restrict__ tidx,
    const float* __restrict__ e2buf, const float* __restrict__ sbuf,
    const float* __restrict__ xrt, float* __restrict__ xclass, int NC) {
    int lane = threadIdx.x & 63;
    int c = blockIdx.x * 4 + (threadIdx.x >> 6);
    if (c >= NC) return;
    int n = cnt[c];
    if (n == 0) {
        xclass[(size_t)c * 128 + lane] = 0.f;
        xclass[(size_t)c * 128 + 64 + lane] = 0.f;
        return;
    }
    int base = off[c];
    // pass A: segment max and exp-sum
    float m = -3.4e38f;
    for (int j = lane; j < n; j += 64) m = fmaxf(m, e2buf[elist[base + j]]);
    m = wredmax(m);
    float s = 0.f;
    for (int j = lane; j < n; j += 64) s += expf(e2buf[elist[base + j]] - m);
    s = wred(s);
    float inv = 1.f / (s + 1e-16f);
    // pass B: weighted row accumulation
    float a0 = 0.f, a1 = 0.f;
    for (int j0 = 0; j0 < n; j0 += 64) {
        int lim = n - j0;
        if (lim > 64) lim = 64;
        float wv = 0.f;
        int g = 0;
        if (lane < lim) {
            int e = elist[base + j0 + lane];
            wv = expf(e2buf[e] - m) * inv;
            int te = tidx[e];
            wv *= sbuf[te];
            g = tidx[te];
        }
        for (int jj = 0; jj < lim; jj++) {
            float wj = __shfl(wv, jj);
            int gj = __shfl(g, jj);
            a0 = fmaf(wj, xrt[(size_t)gj * 128 + lane], a0);
            a1 = fmaf(wj, xrt[(size_t)gj * 128 + 64 + lane], a1);
        }
    }
    xclass[(size_t)c * 128 + lane] = a0;
    xclass[(size_t)c * 128 + 64 + lane] = a1;
}

// ---- level 3: class -> head entity ----
__global__ __launch_bounds__(256) void k_class1(
    const float* __restrict__ xclass, const float* __restrict__ ac,
    const float* __restrict__ eh4, const int* __restrict__ hclass,
    float* __restrict__ zc, unsigned* __restrict__ m3, int NC) {
    int lane = threadIdx.x & 63;
    int c = blockIdx.x * 4 + (threadIdx.x >> 6);
    if (c >= NC) return;
    float v0 = xclass[(size_t)c * 128 + lane], v1 = xclass[(size_t)c * 128 + 64 + lane];
    float p = wred(v0 * ac[lane] + v1 * ac[64 + lane]);
    if (lane == 0) {
        int hc = hclass[c];
        float z = LRELU(p + eh4[hc]);
        zc[c] = z;
        atomicMax(&m3[hc], fenc(z));
    }
}

__global__ __launch_bounds__(256) void k_class2(const int* __restrict__ hclass,
                                                float* __restrict__ zc,
                                                const unsigned* __restrict__ m3,
                                                float* __restrict__ s3, int NC) {
    int c = blockIdx.x * 256 + threadIdx.x;
    if (c >= NC) return;
    int hc = hclass[c];
    float ex = expf(zc[c] - fdec(m3[hc]));
    zc[c] = ex;
    atomicAdd(&s3[hc], ex);
}

__global__ __launch_bounds__(256) void k_class3(
    const int* __restrict__ hclass, const float* __restrict__ zc,
    const float* __restrict__ s3, const float* __restrict__ xclass,
    float* __restrict__ xeh, int NC) {
    int lane = threadIdx.x & 63;
    int c = blockIdx.x * 4 + (threadIdx.x >> 6);
    if (c >= NC) return;
    int hc = hclass[c];
    float gama = zc[c] / (s3[hc] + 1e-16f);
    float v0 = xclass[(size_t)c * 128 + lane], v1 = xclass[(size_t)c * 128 + 64 + lane];
    atomicAdd(&xeh[(size_t)hc * 128 + lane], gama * v0);
    atomicAdd(&xeh[(size_t)hc * 128 + 64 + lane], gama * v1);
}

extern "C" void kernel_launch(void* const* d_in, const int* in_sizes, int n_in,
                              void* d_out, int out_size, void* d_ws, size_t ws_size,
                              hipStream_t stream) {
    (void)n_in; (void)out_size; (void)ws_size;
    const float* xe   = (const float*)d_in[0];
    const int*   eidx = (const int*)d_in[1];
    const int*   rel  = (const int*)d_in[2];
    const int*   tnum = (const int*)d_in[3];
    const float* remb = (const float*)d_in[4];
    const int*   cidx = (const int*)d_in[5];
    const int*   hcls = (const int*)d_in[6];
    const float* ah1  = (const float*)d_in[7];
    const float* ah2  = (const float*)d_in[8];
    const float* ah3  = (const float*)d_in[9];
    const float* ah4  = (const float*)d_in[10];
    const float* at1  = (const float*)d_in[11];
    const float* at2  = (const float*)d_in[12];
    const float* at3  = (const float*)d_in[13];
    const float* ar1  = (const float*)d_in[14];
    const float* ar2  = (const float*)d_in[15];
    const float* ac   = (const float*)d_in[16];
    const float* wh   = (const float*)d_in[17];
    const float* wt   = (const float*)d_in[18];
    const float* hww  = (const float*)d_in[19];
    const float* hwb  = (const float*)d_in[20];
    float* out = (float*)d_out;

    const int NE = in_sizes[0] / 256;
    const int E  = in_sizes[2];
    const int NR = in_sizes[4] / 128;
    const int NC = in_sizes[6];
    const int* hidx = eidx;
    const int* tidx = eidx + E;

    char* base = (char*)d_ws;
    size_t off0 = 0;
    auto alloc = [&](size_t bytes) -> char* {
        char* r = base + off0;
        off0 = (off0 + bytes + 255) & ~(size_t)255;
        return r;
    };
    float* xrh  = (float*)alloc((size_t)NE * 128 * 4);
    float* xrt  = (float*)alloc((size_t)NE * 128 * 4);
    float* eh1  = (float*)alloc((size_t)NE * 4);
    float* eh2  = (float*)alloc((size_t)NE * 4);
    float* eh3  = (float*)alloc((size_t)NE * 4);
    float* eh4  = (float*)alloc((size_t)NE * 4);
    float* et1b = (float*)alloc((size_t)NE * 4);
    float* et2b = (float*)alloc((size_t)NE * 4);
    float* et3b = (float*)alloc((size_t)NE * 4);
    float* nrmb = (float*)alloc((size_t)NE * 4);
    float* er1b = (float*)alloc((size_t)NR * 4);
    float* er2b = (float*)alloc((size_t)NR * 4);
    float* zbuf  = (float*)alloc((size_t)E * 4);
    float* e2buf = (float*)alloc((size_t)E * 4);
    float* sbuf  = (float*)alloc((size_t)E * 4);
    float* zc    = (float*)alloc((size_t)NC * 4);
    unsigned short* wtb_hi = (unsigned short*)alloc((size_t)256 * 256 * 2);
    unsigned short* wtb_lo = (unsigned short*)alloc((size_t)256 * 256 * 2);
    unsigned short* hwt_hi = (unsigned short*)alloc((size_t)128 * 128 * 2);
    unsigned short* hwt_lo = (unsigned short*)alloc((size_t)128 * 128 * 2);
    int* offb  = (int*)alloc((size_t)NC * 4);
    int* curb  = (int*)alloc((size_t)NC * 4);
    int* elist = (int*)alloc((size_t)E * 4);
    float* xclass = (float*)alloc((size_t)NC * 128 * 4);
    size_t zoff = off0;  // everything below is zero-initialized per launch
    unsigned* m1 = (unsigned*)alloc((size_t)NE * 4);
    float* s1    = (float*)alloc((size_t)NE * 4);
    unsigned* m3 = (unsigned*)alloc((size_t)NE * 4);
    float* s3    = (float*)alloc((size_t)NE * 4);
    int* cntb    = (int*)alloc((size_t)NC * 4);
    float* xeh   = (float*)alloc((size_t)NE * 128 * 4);
    size_t zbytes = off0 - zoff;

    hipMemsetAsync(base + zoff, 0, zbytes, stream);

    k_convW<<<(256 * 256 + 128 * 128 + 255) / 256, 256, 0, stream>>>(
        wh, wt, hww, wtb_hi, wtb_lo, hwt_hi, hwt_lo);
    k_rel<<<(NR + 3) / 4, 256, 0, stream>>>(remb, ar1, ar2, er1b, er2b, NR);

    // projection GEMM with fused per-entity dots + norm
    k_gemm<256, 0><<<(NE + 63) / 64, 256, 0, stream>>>(
        xe, wtb_hi, wtb_lo, xrh, xrt, nullptr, nullptr, NE,
        ah1, ah2, ah3, ah4, at1, at2, at3,
        eh1, eh2, eh3, eh4, et1b, et2b, et3b, nrmb);

    // class-CSR build (independent of edge kernels)
    k_hist<<<(E + 255) / 256, 256, 0, stream>>>(cidx, cntb, E);
    k_scan<<<1, 1024, 0, stream>>>(cntb, offb, curb, NC);
    k_scatter<<<(E + 255) / 256, 256, 0, stream>>>(cidx, curb, elist, E);

    k_edge1<<<(E + 255) / 256, 256, 0, stream>>>(hidx, tidx, rel, tnum, eh1, et1b, er1b, zbuf, m1, E);
    k_edge2<<<(E + 255) / 256, 256, 0, stream>>>(tnum, zbuf, m1, s1, E);
    k_edge3<<<(E + 255) / 256, 256, 0, stream>>>(hidx, tidx, rel, tnum, zbuf, s1, nrmb,
                                                 eh2, eh3, et2b, et3b, er2b, sbuf, e2buf, E);
    k_spmm2<<<(NC + 3) / 4, 256, 0, stream>>>(elist, offb, cntb, tidx, e2buf, sbuf,
                                              xrt, xclass, NC);
    k_class1<<<(NC + 3) / 4, 256, 0, stream>>>(xclass, ac, eh4, hcls, zc, m3, NC);
    k_class2<<<(NC + 255) / 256, 256, 0, stream>>>(hcls, zc, m3, s3, NC);
    k_class3<<<(NC + 3) / 4, 256, 0, stream>>>(hcls, zc, s3, xclass, xeh, NC);

    k_gemm<128, 1><<<(NE + 127) / 128, 256, 0, stream>>>(
        xrh, hwt_hi, hwt_lo, out, nullptr, hwb, xeh, NE,
        nullptr, nullptr, nullptr, nullptr, nullptr, nullptr, nullptr,
        nullptr, nullptr, nullptr, nullptr, nullptr, nullptr, nullptr, nullptr);
}

// Round 6
// 657.114 us; speedup vs baseline: 2.2433x; 1.0202x over previous
//
#include <hip/hip_runtime.h>
#include <hip/hip_bf16.h>

#define LRELU(x) ((x) >= 0.f ? (x) : 0.01f * (x))

typedef __attribute__((ext_vector_type(8))) short short8v;
typedef __attribute__((ext_vector_type(4))) float f32x4;

__device__ inline unsigned fenc(float x) {
    unsigned u = __float_as_uint(x);
    return (u & 0x80000000u) ? ~u : (u | 0x80000000u);
}
__device__ inline float fdec(unsigned e) {
    return __uint_as_float((e & 0x80000000u) ? (e ^ 0x80000000u) : ~e);
}

__device__ inline float wred(float v) {
#pragma unroll
    for (int o = 32; o > 0; o >>= 1) v += __shfl_xor(v, o, 64);
    return v;
}
__device__ inline float wredmax(float v) {
#pragma unroll
    for (int o = 32; o > 0; o >>= 1) v = fmaxf(v, __shfl_xor(v, o, 64));
    return v;
}

__device__ inline unsigned short f2bu(float x) {
    __hip_bfloat16 b = __float2bfloat16(x);
    return *reinterpret_cast<unsigned short*>(&b);
}
__device__ inline float bu2f(unsigned short u) {
    return __uint_as_float((unsigned)u << 16);
}

__device__ inline f32x4 mfma16(short8v a, short8v b, f32x4 c) {
    return __builtin_amdgcn_mfma_f32_16x16x32_bf16(a, b, c, 0, 0, 0);
}

// ---- convert W matrices to transposed hi/lo bf16: Wt[n][k] = W[k][n] ----
__global__ __launch_bounds__(256) void k_convW(
    const float* __restrict__ wh, const float* __restrict__ wt,
    const float* __restrict__ hww, unsigned short* __restrict__ wtb_hi,
    unsigned short* __restrict__ wtb_lo, unsigned short* __restrict__ hwt_hi,
    unsigned short* __restrict__ hwt_lo) {
    int id = blockIdx.x * 256 + threadIdx.x;
    if (id < 256 * 256) {
        int n = id >> 8, k = id & 255;
        float v = (n < 128) ? wh[(size_t)k * 128 + n] : wt[(size_t)k * 128 + (n - 128)];
        unsigned short h = f2bu(v);
        float r = v - bu2f(h);
        wtb_hi[(size_t)n * 256 + k] = h;
        wtb_lo[(size_t)n * 256 + k] = f2bu(r);
    } else {
        int id2 = id - 256 * 256;
        if (id2 < 128 * 128) {
            int n = id2 >> 7, k = id2 & 127;
            float v = hww[(size_t)k * 128 + n];
            unsigned short h = f2bu(v);
            float r = v - bu2f(h);
            hwt_hi[(size_t)n * 128 + k] = h;
            hwt_lo[(size_t)n * 128 + k] = f2bu(r);
        }
    }
}

// ---- split-bf16 MFMA GEMM, small wave tile (32x64) for occupancy ----
// Block = 64 rows x 128 cols, 4 waves = 2 rowgroups x 2 col-halves(64).
// EPI 0 (proj, KD=256): blockIdx.x = mblk*2 + half; half 0 -> o0=xrh (w_h cols),
//   half 1 -> o1=xrt (w_t cols). relu + fused per-row dots (LDS cross-wave add).
// EPI 1 (highway, KD=128, N=128): gate = sigmoid(C+bias); o0 = g*xeh + (1-g)*A.
template <int KD, int EPI>
__global__ __launch_bounds__(256) void k_gemm(
    const float* __restrict__ A, const unsigned short* __restrict__ Bh,
    const unsigned short* __restrict__ Bl, float* __restrict__ o0,
    float* __restrict__ o1, const float* __restrict__ bias,
    const float* __restrict__ xeh, int M,
    const float* __restrict__ av1, const float* __restrict__ av2,
    const float* __restrict__ av3, const float* __restrict__ av4,
    const float* __restrict__ bv1, const float* __restrict__ bv2,
    const float* __restrict__ bv3, float* __restrict__ d1o,
    float* __restrict__ d2o, float* __restrict__ d3o, float* __restrict__ d4o,
    float* __restrict__ e1o, float* __restrict__ e2o, float* __restrict__ e3o,
    float* __restrict__ nrmo) {
    __shared__ float pd[2][64][4];
    int bx = blockIdx.x;
    int half = (EPI == 0) ? (bx & 1) : 0;
    int mblk = (EPI == 0) ? (bx >> 1) : bx;
    int row0 = mblk * 64;
    if (row0 + 64 > M) row0 = M - 64;
    int tid = threadIdx.x;
    int w = tid >> 6, l = tid & 63;
    int rg = w >> 1, ch = w & 1;
    int lr = l & 15, hi4 = l >> 4;
    int lk = hi4 * 8;

    f32x4 acc[2][4];
#pragma unroll
    for (int i = 0; i < 2; i++)
#pragma unroll
        for (int j = 0; j < 4; j++) acc[i][j] = (f32x4){0.f, 0.f, 0.f, 0.f};

    const float* ap0 = A + (size_t)(row0 + rg * 32 + lr) * KD + lk;
    const float* ap1 = ap0 + (size_t)16 * KD;
    const unsigned short* bp_h = Bh + (size_t)(half * 128 + ch * 64 + lr) * KD + lk;
    const unsigned short* bp_l = Bl + (size_t)(half * 128 + ch * 64 + lr) * KD + lk;

    float4 nx[2][2];
    nx[0][0] = *(const float4*)ap0;
    nx[0][1] = *(const float4*)(ap0 + 4);
    nx[1][0] = *(const float4*)ap1;
    nx[1][1] = *(const float4*)(ap1 + 4);

    for (int k0 = 0; k0 < KD; k0 += 32) {
        float4 cx[2][2];
        cx[0][0] = nx[0][0]; cx[0][1] = nx[0][1];
        cx[1][0] = nx[1][0]; cx[1][1] = nx[1][1];
        if (k0 + 32 < KD) {  // depth-1 prefetch of next A tile
            nx[0][0] = *(const float4*)(ap0 + k0 + 32);
            nx[0][1] = *(const float4*)(ap0 + k0 + 36);
            nx[1][0] = *(const float4*)(ap1 + k0 + 32);
            nx[1][1] = *(const float4*)(ap1 + k0 + 36);
        }
        short8v ah[2], al[2];
#pragma unroll
        for (int rf = 0; rf < 2; rf++) {
            float xs[8] = {cx[rf][0].x, cx[rf][0].y, cx[rf][0].z, cx[rf][0].w,
                           cx[rf][1].x, cx[rf][1].y, cx[rf][1].z, cx[rf][1].w};
#pragma unroll
            for (int j = 0; j < 8; j++) {
                unsigned short hu = f2bu(xs[j]);
                ah[rf][j] = (short)hu;
                al[rf][j] = (short)f2bu(xs[j] - bu2f(hu));
            }
        }
#pragma unroll
        for (int cf = 0; cf < 4; cf++) {
            short8v bh = *(const short8v*)(bp_h + (size_t)(cf * 16) * KD + k0);
            short8v bl = *(const short8v*)(bp_l + (size_t)(cf * 16) * KD + k0);
#pragma unroll
            for (int rf = 0; rf < 2; rf++) {
                acc[rf][cf] = mfma16(ah[rf], bh, acc[rf][cf]);
                acc[rf][cf] = mfma16(al[rf], bh, acc[rf][cf]);
                acc[rf][cf] = mfma16(ah[rf], bl, acc[rf][cf]);
            }
        }
    }

    if (EPI == 0) {
        float* O = half ? o1 : o0;
        const float* v1 = half ? bv1 : av1;
        const float* v2 = half ? bv2 : av2;
        const float* v3 = half ? bv3 : av3;
#pragma unroll
        for (int rf = 0; rf < 2; rf++)
#pragma unroll
            for (int r = 0; r < 4; r++) {
                int rl = rg * 32 + rf * 16 + hi4 * 4 + r;
                int row = row0 + rl;
                float d0 = 0.f, d1 = 0.f, d2 = 0.f, d3 = 0.f;
#pragma unroll
                for (int cf = 0; cf < 4; cf++) {
                    float v = fmaxf(acc[rf][cf][r], 0.f);
                    int col = ch * 64 + cf * 16 + lr;
                    O[(size_t)row * 128 + col] = v;
                    d0 = fmaf(v, v1[col], d0);
                    d1 = fmaf(v, v2[col], d1);
                    d2 = fmaf(v, v3[col], d2);
                    d3 = fmaf(v, half ? v : av4[col], d3);
                }
#pragma unroll
                for (int o = 1; o <= 8; o <<= 1) {
                    d0 += __shfl_xor(d0, o, 64);
                    d1 += __shfl_xor(d1, o, 64);
                    d2 += __shfl_xor(d2, o, 64);
                    d3 += __shfl_xor(d3, o, 64);
                }
                if (lr == 0) {
                    pd[ch][rl][0] = d0; pd[ch][rl][1] = d1;
                    pd[ch][rl][2] = d2; pd[ch][rl][3] = d3;
                }
            }
        __syncthreads();
        if (ch == 0) {
#pragma unroll
            for (int rf = 0; rf < 2; rf++)
#pragma unroll
                for (int r = 0; r < 4; r++) {
                    int rl = rg * 32 + rf * 16 + hi4 * 4 + r;
                    int row = row0 + rl;
                    if (lr == 0) {
                        float s0 = pd[0][rl][0] + pd[1][rl][0];
                        float s1 = pd[0][rl][1] + pd[1][rl][1];
                        float s2 = pd[0][rl][2] + pd[1][rl][2];
                        float s3 = pd[0][rl][3] + pd[1][rl][3];
                        if (half == 0) {
                            d1o[row] = s0; d2o[row] = s1; d3o[row] = s2; d4o[row] = s3;
                        } else {
                            e1o[row] = s0; e2o[row] = s1; e3o[row] = s2;
                            nrmo[row] = sqrtf(s3);
                        }
                    }
                }
        }
    } else {
#pragma unroll
        for (int rf = 0; rf < 2; rf++)
#pragma unroll
            for (int cf = 0; cf < 4; cf++)
#pragma unroll
                for (int r = 0; r < 4; r++) {
                    int row = row0 + rg * 32 + rf * 16 + hi4 * 4 + r;
                    int col = ch * 64 + cf * 16 + lr;
                    float a = acc[rf][cf][r] + bias[col];
                    float g = 1.f / (1.f + expf(-a));
                    size_t o = (size_t)row * 128 + col;
                    o0[o] = g * xeh[o] + (1.f - g) * A[o];
                }
    }
}

// ---- relation dots ----
__global__ __launch_bounds__(256) void k_rel(const float* __restrict__ remb,
                                             const float* __restrict__ ar1,
                                             const float* __restrict__ ar2,
                                             float* __restrict__ er1,
                                             float* __restrict__ er2, int NR) {
    int lane = threadIdx.x & 63;
    int r = blockIdx.x * 4 + (threadIdx.x >> 6);
    if (r >= NR) return;
    float v0 = remb[(size_t)r * 128 + lane];
    float v1 = remb[(size_t)r * 128 + 64 + lane];
    float p1 = v0 * ar1[lane] + v1 * ar1[64 + lane];
    float p2 = v0 * ar2[lane] + v1 * ar2[64 + lane];
    p1 = wred(p1);
    p2 = wred(p2);
    if (lane == 0) { er1[r] = p1; er2[r] = p2; }
}

// ---- level 1 softmax over triple_num segments ----
__global__ __launch_bounds__(256) void k_edge1(
    const int* __restrict__ hidx, const int* __restrict__ tidx,
    const int* __restrict__ rel, const int* __restrict__ tnum,
    const float* __restrict__ eh1, const float* __restrict__ et1,
    const float* __restrict__ er1, float* __restrict__ zbuf,
    unsigned* __restrict__ m1, int E) {
    int i = blockIdx.x * 256 + threadIdx.x;
    if (i >= E) return;
    float e1 = 0.5f * (eh1[hidx[i]] + et1[tidx[i]]) + er1[rel[i]];
    float z = LRELU(e1);
    zbuf[i] = z;
    atomicMax(&m1[tnum[i]], fenc(z));
}

__global__ __launch_bounds__(256) void k_edge2(const int* __restrict__ tnum,
                                               float* __restrict__ zbuf,
                                               const unsigned* __restrict__ m1,
                                               float* __restrict__ s1, int E) {
    int i = blockIdx.x * 256 + threadIdx.x;
    if (i >= E) return;
    int tn = tnum[i];
    float ex = expf(zbuf[i] - fdec(m1[tn]));
    zbuf[i] = ex;
    atomicAdd(&s1[tn], ex);
}

// ---- alpha -> per-edge scale s, level-2 logit z2 (no atomics) ----
__global__ __launch_bounds__(256) void k_edge3(
    const int* __restrict__ hidx, const int* __restrict__ tidx,
    const int* __restrict__ rel, const int* __restrict__ tnum,
    const float* __restrict__ zbuf, const float* __restrict__ s1,
    const float* __restrict__ nrm, const float* __restrict__ eh2,
    const float* __restrict__ eh3, const float* __restrict__ et2,
    const float* __restrict__ et3, const float* __restrict__ er2,
    float* __restrict__ sbuf, float* __restrict__ e2buf, int E) {
    int i = blockIdx.x * 256 + threadIdx.x;
    if (i >= E) return;
    float alpha = zbuf[i] / (s1[tnum[i]] + 1e-16f);
    int t = tidx[i];
    float s = alpha / fmaxf(alpha * nrm[t], 1e-12f);
    sbuf[i] = s;
    int h = hidx[i];
    float z2 = s * et2[t] + eh2[h] + 0.5f * (er2[rel[i]] + 0.5f * (eh3[h] + s * et3[t]));
    e2buf[i] = LRELU(z2);
}

// ---- counting sort by class_index ----
__global__ __launch_bounds__(256) void k_hist(const int* __restrict__ cidx,
                                              int* __restrict__ cnt, int E) {
    int i = blockIdx.x * 256 + threadIdx.x;
    if (i >= E) return;
    atomicAdd(&cnt[cidx[i]], 1);
}

__global__ __launch_bounds__(1024) void k_scan(const int* __restrict__ cnt,
                                               int* __restrict__ off,
                                               int* __restrict__ cur, int NC) {
    __shared__ int wt[16];
    __shared__ int sbase;
    int tid = threadIdx.x, w = tid >> 6, lane = tid & 63;
    if (tid == 0) sbase = 0;
    __syncthreads();
    for (int c0 = 0; c0 < NC; c0 += 1024) {
        int c = c0 + tid;
        int v = (c < NC) ? cnt[c] : 0;
        int x = v;
#pragma unroll
        for (int o = 1; o < 64; o <<= 1) {
            int t = __shfl_up(x, o, 64);
            if (lane >= o) x += t;
        }
        if (lane == 63) wt[w] = x;
        __syncthreads();
        int pre = 0, tot = 0;
#pragma unroll
        for (int i = 0; i < 16; i++) {
            int t = wt[i];
            tot += t;
            if (i < w) pre += t;
        }
        int excl = sbase + pre + x - v;
        if (c < NC) { off[c] = excl; cur[c] = excl; }
        __syncthreads();
        if (tid == 0) sbase += tot;
        __syncthreads();
    }
}

__global__ __launch_bounds__(256) void k_scatter(const int* __restrict__ cidx,
                                                 int* __restrict__ cur,
                                                 int* __restrict__ elist, int E) {
    int i = blockIdx.x * 256 + threadIdx.x;
    if (i >= E) return;
    int pos = atomicAdd(&cur[cidx[i]], 1);
    elist[pos] = i;
}

// ---- fused level-2 softmax + spmm, one wave per class, batched gathers ----
__global__ __launch_bounds__(256) void k_spmm2(
    const int* __restrict__ elist, const int* __restrict__ off,
    const int* __restrict__ cnt, const int* __restrict__ tidx,
    const float* __restrict__ e2buf, const float* __restrict__ sbuf,
    const float* __restrict__ xrt, float* __restrict__ xclass, int NC) {
    int lane = threadIdx.x & 63;
    int c = blockIdx.x * 4 + (threadIdx.x >> 6);
    if (c >= NC) return;
    int n = cnt[c];
    if (n == 0) {
        xclass[(size_t)c * 128 + lane] = 0.f;
        xclass[(size_t)c * 128 + 64 + lane] = 0.f;
        return;
    }
    int base = off[c];
    float m = -3.4e38f;
    for (int j = lane; j < n; j += 64) m = fmaxf(m, e2buf[elist[base + j]]);
    m = wredmax(m);
    float s = 0.f;
    for (int j = lane; j < n; j += 64) s += expf(e2buf[elist[base + j]] - m);
    s = wred(s);
    float inv = 1.f / (s + 1e-16f);
    float a0 = 0.f, a1 = 0.f;
    for (int j0 = 0; j0 < n; j0 += 64) {
        int lim = n - j0;
        if (lim > 64) lim = 64;
        float wv = 0.f;
        int g = 0;
        if (lane < lim) {
            int e = elist[base + j0 + lane];
            wv = expf(e2buf[e] - m) * inv;
            int te = tidx[e];
            wv *= sbuf[te];
            g = tidx[te];
        }
        int jj = 0;
        for (; jj + 8 <= lim; jj += 8) {  // 16 outstanding gathers
            float w0 = __shfl(wv, jj + 0), w1 = __shfl(wv, jj + 1);
            float w2 = __shfl(wv, jj + 2), w3 = __shfl(wv, jj + 3);
            float w4 = __shfl(wv, jj + 4), w5 = __shfl(wv, jj + 5);
            float w6 = __shfl(wv, jj + 6), w7 = __shfl(wv, jj + 7);
            const float* p0 = xrt + (size_t)__shfl(g, jj + 0) * 128 + lane;
            const float* p1 = xrt + (size_t)__shfl(g, jj + 1) * 128 + lane;
            const float* p2 = xrt + (size_t)__shfl(g, jj + 2) * 128 + lane;
            const float* p3 = xrt + (size_t)__shfl(g, jj + 3) * 128 + lane;
            const float* p4 = xrt + (size_t)__shfl(g, jj + 4) * 128 + lane;
            const float* p5 = xrt + (size_t)__shfl(g, jj + 5) * 128 + lane;
            const float* p6 = xrt + (size_t)__shfl(g, jj + 6) * 128 + lane;
            const float* p7 = xrt + (size_t)__shfl(g, jj + 7) * 128 + lane;
            float x0 = p0[0], y0 = p0[64], x1 = p1[0], y1 = p1[64];
            float x2 = p2[0], y2 = p2[64], x3 = p3[0], y3 = p3[64];
            float x4 = p4[0], y4 = p4[64], x5 = p5[0], y5 = p5[64];
            float x6 = p6[0], y6 = p6[64], x7 = p7[0], y7 = p7[64];
            a0 = fmaf(w0, x0, a0); a1 = fmaf(w0, y0, a1);
            a0 = fmaf(w1, x1, a0); a1 = fmaf(w1, y1, a1);
            a0 = fmaf(w2, x2, a0); a1 = fmaf(w2, y2, a1);
            a0 = fmaf(w3, x3, a0); a1 = fmaf(w3, y3, a1);
            a0 = fmaf(w4, x4, a0); a1 = fmaf(w4, y4, a1);
            a0 = fmaf(w5, x5, a0); a1 = fmaf(w5, y5, a1);
            a0 = fmaf(w6, x6, a0); a1 = fmaf(w6, y6, a1);
            a0 = fmaf(w7, x7, a0); a1 = fmaf(w7, y7, a1);
        }
        for (; jj < lim; jj++) {
            float wj = __shfl(wv, jj);
            int gj = __shfl(g, jj);
            a0 = fmaf(wj, xrt[(size_t)gj * 128 + lane], a0);
            a1 = fmaf(wj, xrt[(size_t)gj * 128 + 64 + lane], a1);
        }
    }
    xclass[(size_t)c * 128 + lane] = a0;
    xclass[(size_t)c * 128 + 64 + lane] = a1;
}

// ---- level 3: class -> head entity ----
__global__ __launch_bounds__(256) void k_class1(
    const float* __restrict__ xclass, const float* __restrict__ ac,
    const float* __restrict__ eh4, const int* __restrict__ hclass,
    float* __restrict__ zc, unsigned* __restrict__ m3, int NC) {
    int lane = threadIdx.x & 63;
    int c = blockIdx.x * 4 + (threadIdx.x >> 6);
    if (c >= NC) return;
    float v0 = xclass[(size_t)c * 128 + lane], v1 = xclass[(size_t)c * 128 + 64 + lane];
    float p = wred(v0 * ac[lane] + v1 * ac[64 + lane]);
    if (lane == 0) {
        int hc = hclass[c];
        float z = LRELU(p + eh4[hc]);
        zc[c] = z;
        atomicMax(&m3[hc], fenc(z));
    }
}

__global__ __launch_bounds__(256) void k_class2(const int* __restrict__ hclass,
                                                float* __restrict__ zc,
                                                const unsigned* __restrict__ m3,
                                                float* __restrict__ s3, int NC) {
    int c = blockIdx.x * 256 + threadIdx.x;
    if (c >= NC) return;
    int hc = hclass[c];
    float ex = expf(zc[c] - fdec(m3[hc]));
    zc[c] = ex;
    atomicAdd(&s3[hc], ex);
}

__global__ __launch_bounds__(256) void k_class3(
    const int* __restrict__ hclass, const float* __restrict__ zc,
    const float* __restrict__ s3, const float* __restrict__ xclass,
    float* __restrict__ xeh, int NC) {
    int lane = threadIdx.x & 63;
    int c = blockIdx.x * 4 + (threadIdx.x >> 6);
    if (c >= NC) return;
    int hc = hclass[c];
    float gama = zc[c] / (s3[hc] + 1e-16f);
    float v0 = xclass[(size_t)c * 128 + lane], v1 = xclass[(size_t)c * 128 + 64 + lane];
    atomicAdd(&xeh[(size_t)hc * 128 + lane], gama * v0);
    atomicAdd(&xeh[(size_t)hc * 128 + 64 + lane], gama * v1);
}

extern "C" void kernel_launch(void* const* d_in, const int* in_sizes, int n_in,
                              void* d_out, int out_size, void* d_ws, size_t ws_size,
                              hipStream_t stream) {
    (void)n_in; (void)out_size; (void)ws_size;
    const float* xe   = (const float*)d_in[0];
    const int*   eidx = (const int*)d_in[1];
    const int*   rel  = (const int*)d_in[2];
    const int*   tnum = (const int*)d_in[3];
    const float* remb = (const float*)d_in[4];
    const int*   cidx = (const int*)d_in[5];
    const int*   hcls = (const int*)d_in[6];
    const float* ah1  = (const float*)d_in[7];
    const float* ah2  = (const float*)d_in[8];
    const float* ah3  = (const float*)d_in[9];
    const float* ah4  = (const float*)d_in[10];
    const float* at1  = (const float*)d_in[11];
    const float* at2  = (const float*)d_in[12];
    const float* at3  = (const float*)d_in[13];
    const float* ar1  = (const float*)d_in[14];
    const float* ar2  = (const float*)d_in[15];
    const float* ac   = (const float*)d_in[16];
    const float* wh   = (const float*)d_in[17];
    const float* wt   = (const float*)d_in[18];
    const float* hww  = (const float*)d_in[19];
    const float* hwb  = (const float*)d_in[20];
    float* out = (float*)d_out;

    const int NE = in_sizes[0] / 256;
    const int E  = in_sizes[2];
    const int NR = in_sizes[4] / 128;
    const int NC = in_sizes[6];
    const int* hidx = eidx;
    const int* tidx = eidx + E;

    char* base = (char*)d_ws;
    size_t off0 = 0;
    auto alloc = [&](size_t bytes) -> char* {
        char* r = base + off0;
        off0 = (off0 + bytes + 255) & ~(size_t)255;
        return r;
    };
    float* xrh  = (float*)alloc((size_t)NE * 128 * 4);
    float* xrt  = (float*)alloc((size_t)NE * 128 * 4);
    float* eh1  = (float*)alloc((size_t)NE * 4);
    float* eh2  = (float*)alloc((size_t)NE * 4);
    float* eh3  = (float*)alloc((size_t)NE * 4);
    float* eh4  = (float*)alloc((size_t)NE * 4);
    float* et1b = (float*)alloc((size_t)NE * 4);
    float* et2b = (float*)alloc((size_t)NE * 4);
    float* et3b = (float*)alloc((size_t)NE * 4);
    float* nrmb = (float*)alloc((size_t)NE * 4);
    float* er1b = (float*)alloc((size_t)NR * 4);
    float* er2b = (float*)alloc((size_t)NR * 4);
    float* zbuf  = (float*)alloc((size_t)E * 4);
    float* e2buf = (float*)alloc((size_t)E * 4);
    float* sbuf  = (float*)alloc((size_t)E * 4);
    float* zc    = (float*)alloc((size_t)NC * 4);
    unsigned short* wtb_hi = (unsigned short*)alloc((size_t)256 * 256 * 2);
    unsigned short* wtb_lo = (unsigned short*)alloc((size_t)256 * 256 * 2);
    unsigned short* hwt_hi = (unsigned short*)alloc((size_t)128 * 128 * 2);
    unsigned short* hwt_lo = (unsigned short*)alloc((size_t)128 * 128 * 2);
    int* offb  = (int*)alloc((size_t)NC * 4);
    int* curb  = (int*)alloc((size_t)NC * 4);
    int* elist = (int*)alloc((size_t)E * 4);
    float* xclass = (float*)alloc((size_t)NC * 128 * 4);
    size_t zoff = off0;  // everything below is zero-initialized per launch
    unsigned* m1 = (unsigned*)alloc((size_t)NE * 4);
    float* s1    = (float*)alloc((size_t)NE * 4);
    unsigned* m3 = (unsigned*)alloc((size_t)NE * 4);
    float* s3    = (float*)alloc((size_t)NE * 4);
    int* cntb    = (int*)alloc((size_t)NC * 4);
    float* xeh   = (float*)alloc((size_t)NE * 128 * 4);
    size_t zbytes = off0 - zoff;

    hipMemsetAsync(base + zoff, 0, zbytes, stream);

    k_convW<<<(256 * 256 + 128 * 128 + 255) / 256, 256, 0, stream>>>(
        wh, wt, hww, wtb_hi, wtb_lo, hwt_hi, hwt_lo);
    k_rel<<<(NR + 3) / 4, 256, 0, stream>>>(remb, ar1, ar2, er1b, er2b, NR);

    // projection GEMM with fused per-entity dots + norm (2 blocks per 64 rows)
    k_gemm<256, 0><<<((NE + 63) / 64) * 2, 256, 0, stream>>>(
        xe, wtb_hi, wtb_lo, xrh, xrt, nullptr, nullptr, NE,
        ah1, ah2, ah3, ah4, at1, at2, at3,
        eh1, eh2, eh3, eh4, et1b, et2b, et3b, nrmb);

    // class-CSR build (independent of edge kernels)
    k_hist<<<(E + 255) / 256, 256, 0, stream>>>(cidx, cntb, E);
    k_scan<<<1, 1024, 0, stream>>>(cntb, offb, curb, NC);
    k_scatter<<<(E + 255) / 256, 256, 0, stream>>>(cidx, curb, elist, E);

    k_edge1<<<(E + 255) / 256, 256, 0, stream>>>(hidx, tidx, rel, tnum, eh1, et1b, er1b, zbuf, m1, E);
    k_edge2<<<(E + 255) / 256, 256, 0, stream>>>(tnum, zbuf, m1, s1, E);
    k_edge3<<<(E + 255) / 256, 256, 0, stream>>>(hidx, tidx, rel, tnum, zbuf, s1, nrmb,
                                                 eh2, eh3, et2b, et3b, er2b, sbuf, e2buf, E);
    k_spmm2<<<(NC + 3) / 4, 256, 0, stream>>>(elist, offb, cntb, tidx, e2buf, sbuf,
                                              xrt, xclass, NC);
    k_class1<<<(NC + 3) / 4, 256, 0, stream>>>(xclass, ac, eh4, hcls, zc, m3, NC);
    k_class2<<<(NC + 255) / 256, 256, 0, stream>>>(hcls, zc, m3, s3, NC);
    k_class3<<<(NC + 3) / 4, 256, 0, stream>>>(hcls, zc, s3, xclass, xeh, NC);

    // BM=64 for EPI 1 as well -> one block per 64 rows (round-5 bug: was /128)
    k_gemm<128, 1><<<(NE + 63) / 64, 256, 0, stream>>>(
        xrh, hwt_hi, hwt_lo, out, nullptr, hwb, xeh, NE,
        nullptr, nullptr, nullptr, nullptr, nullptr, nullptr, nullptr,
        nullptr, nullptr, nullptr, nullptr, nullptr, nullptr, nullptr, nullptr);
}